// Round 1
// baseline (1787.059 us; speedup 1.0000x reference)
//
#include <hip/hip_runtime.h>

#define H_ 256
#define W_ 1216
#define HW_ (H_*W_)
#define B_ 2
#define Ns_ 20000
#define K_ 9
#define D_ 131
#define Dh_ 65

#define LSTR 72      // LDS shorts per position (64 cin + 8 pad; 16B-aligned, even bank spread)
#define TPOS 66      // positions per tile row (64 + 2 halo)

typedef __attribute__((ext_vector_type(8))) short bf16x8;
typedef __attribute__((ext_vector_type(4))) float f32x4;

__device__ __forceinline__ float b2f(unsigned short u){
  union { unsigned int i; float f; } v; v.i = ((unsigned int)u) << 16; return v.f;
}
__device__ __forceinline__ unsigned short f2b(float f){
  union { float f; unsigned int i; } v; v.f = f;
  unsigned int r = (v.i + 0x7FFFu + ((v.i >> 16) & 1u)) >> 16;
  return (unsigned short)r;
}

// ---------------- weight swizzle: fp32 (C,Cin,3,3) -> bf16 MFMA A-frag order ----------------
// Layout: [conv(6)][mtile(4)][kc(18)][lane(64)][j(8)]; k = kc*32 + quad*8 + j; tap=k>>6, cin=k&63
struct WPtrs { const float* w[6]; };

__global__ void prep_w(WPtrs wp, unsigned short* __restrict__ Asw){
  int blk = blockIdx.x;                 // 6*4*18 = 432
  int c = blk / 72, rem = blk % 72, mt = rem / 18, kc = rem % 18;
  int lane = threadIdx.x;               // 64
  const float* w = wp.w[c];
  int co = mt*16 + (lane & 15);
  int kb = kc*32 + (lane >> 4)*8;
  unsigned short* dst = Asw + ((size_t)blk*64 + lane)*8;
  #pragma unroll
  for (int j = 0; j < 8; ++j){
    int k = kb + j, tap = k >> 6, cin = k & 63;
    dst[j] = f2b(w[((size_t)co*64 + cin)*9 + tap]);
  }
}

// ---------------- MLP layer-1 weight swizzle: [dw1|rw1] (131x130) -> bf16 MFMA B-frag order ----
// GEMM: D[m=16][n=144] = feats[16][160] @ W[160][144]; 9 ntiles x 5 ksteps.
// Layout: [ntile*5+ks][lane(64)][jj(8)]; row = ks*32 + (lane>>4)*8 + jj; col = ntile*16 + (lane&15)
__global__ void prep_wmlp(const float* __restrict__ dw1, const float* __restrict__ rw1,
                          unsigned short* __restrict__ Bm){
  int blk = blockIdx.x;                 // 45
  int nt = blk / 5, ks = blk % 5;
  int lane = threadIdx.x;               // 64
  int col = nt*16 + (lane & 15);
  int kb  = ks*32 + (lane >> 4)*8;
  unsigned short* dst = Bm + ((size_t)blk*64 + lane)*8;
  #pragma unroll
  for (int jj = 0; jj < 8; ++jj){
    int row = kb + jj;
    float v = 0.f;
    if (row < D_ && col < 2*Dh_)
      v = (col < Dh_) ? dw1[(size_t)row*Dh_ + col] : rw1[(size_t)row*Dh_ + (col - Dh_)];
    dst[jj] = f2b(v);
  }
}

// ---------------- fused conv0(relu)+conv1, implicit-GEMM MFMA ----------------
// x fp32 NCHW. y0t,u: bf16 (B,HW,64). y1out: fp32 NCHW (= d_out region).
__global__ __launch_bounds__(256,3) void conv01_mfma(
    const float* __restrict__ x,
    const unsigned short* __restrict__ Asw,   // conv0 at +0, conv1 at +36864
    const float* __restrict__ b0, const float* __restrict__ b1,
    unsigned short* __restrict__ y0t, unsigned short* __restrict__ u,
    float* __restrict__ y1out)
{
  __shared__ unsigned short tile[4*TPOS*LSTR];
  int tid = threadIdx.x;
  int c0 = blockIdx.x*64, r0 = blockIdx.y*2, b = blockIdx.z;

  // stage 4 rows x 66 cols x 64 cin, fp32 NCHW -> bf16 [pos][cin]
  {
    int cin = tid >> 2, row = tid & 3;
    int gy = r0 - 1 + row;
    bool rowok = (gy >= 0) && (gy < H_);
    const float* src = x + ((size_t)b*64 + cin)*HW_ + (size_t)gy*W_ + c0 - 1;
    unsigned short* dst = &tile[(size_t)row*TPOS*LSTR + cin];
    #pragma unroll 1
    for (int col = 0; col < TPOS; ++col){
      int gx = c0 - 1 + col;
      float v = (rowok && gx >= 0 && gx < W_) ? src[col] : 0.f;
      dst[col*LSTR] = f2b(v);
    }
  }
  __syncthreads();

  int wave = tid >> 6, lane = tid & 63;
  int quad = lane >> 4, l15 = lane & 15;
  int cobase = (wave & 1)*32;    // wave covers co [cobase, cobase+32)
  int prow = wave >> 1;          // wave covers row r0+prow, cols 0..63

  f32x4 acc[2][2][4];
  #pragma unroll
  for (int cv = 0; cv < 2; ++cv)
    #pragma unroll
    for (int mt = 0; mt < 2; ++mt)
      #pragma unroll
      for (int nt = 0; nt < 4; ++nt)
        acc[cv][mt][nt] = (f32x4){0.f,0.f,0.f,0.f};

  const unsigned short* Ap[2][2];
  #pragma unroll
  for (int cv = 0; cv < 2; ++cv)
    #pragma unroll
    for (int mt = 0; mt < 2; ++mt)
      Ap[cv][mt] = Asw + ((size_t)((cv*4 + (wave&1)*2 + mt)*18)*64 + lane)*8;

  int bbase = (prow*TPOS + l15)*LSTR + quad*8;

  #pragma unroll
  for (int tap = 0; tap < 9; ++tap){
    const int sh = (tap/3)*TPOS + (tap%3);
    #pragma unroll
    for (int cc = 0; cc < 2; ++cc){
      int kc = tap*2 + cc;
      bf16x8 a[2][2], bb[4];
      #pragma unroll
      for (int cv = 0; cv < 2; ++cv)
        #pragma unroll
        for (int mt = 0; mt < 2; ++mt)
          a[cv][mt] = *(const bf16x8*)(Ap[cv][mt] + (size_t)kc*512);
      int boff = bbase + sh*LSTR + cc*32;
      #pragma unroll
      for (int nt = 0; nt < 4; ++nt)
        bb[nt] = *(const bf16x8*)&tile[boff + nt*16*LSTR];
      #pragma unroll
      for (int cv = 0; cv < 2; ++cv)
        #pragma unroll
        for (int mt = 0; mt < 2; ++mt)
          #pragma unroll
          for (int nt = 0; nt < 4; ++nt)
            acc[cv][mt][nt] = __builtin_amdgcn_mfma_f32_16x16x32_bf16(
                a[cv][mt], bb[nt], acc[cv][mt][nt], 0, 0, 0);
    }
  }

  int gy = r0 + prow;
  #pragma unroll
  for (int mt = 0; mt < 2; ++mt){
    int co4 = cobase + mt*16 + quad*4;
    f32x4 bias0 = *(const f32x4*)&b0[co4];
    f32x4 bias1 = *(const f32x4*)&b1[co4];
    #pragma unroll
    for (int nt = 0; nt < 4; ++nt){
      int gx = c0 + nt*16 + l15;
      size_t gpix = (size_t)gy*W_ + gx;
      f32x4 v0 = acc[0][mt][nt] + bias0;
      ushort4 q;
      q.x = f2b(fmaxf(v0.x,0.f)); q.y = f2b(fmaxf(v0.y,0.f));
      q.z = f2b(fmaxf(v0.z,0.f)); q.w = f2b(fmaxf(v0.w,0.f));
      size_t toff = ((size_t)b*HW_ + gpix)*64 + co4;
      *(ushort4*)&y0t[toff] = q;
      *(ushort4*)&u[toff]   = q;
      f32x4 v1 = acc[1][mt][nt] + bias1;
      float* yo = y1out + ((size_t)b*64 + co4)*HW_ + gpix;
      yo[(size_t)0*HW_] = v1.x; yo[(size_t)1*HW_] = v1.y;
      yo[(size_t)2*HW_] = v1.z; yo[(size_t)3*HW_] = v1.w;
    }
  }
}

// ---------------- conv2 + add(out-resident y1) + relu, implicit-GEMM MFMA ----------------
__global__ __launch_bounds__(256,3) void conv2_mfma(
    const unsigned short* __restrict__ ut,    // (B,HW,64) bf16
    const unsigned short* __restrict__ Asw,   // this conv's swizzled base
    const float* __restrict__ bias,
    float* __restrict__ out)                  // fp32 NCHW; holds y1; read-add-write
{
  __shared__ unsigned short tile[4*TPOS*LSTR];
  int tid = threadIdx.x;
  int c0 = blockIdx.x*64, r0 = blockIdx.y*2, b = blockIdx.z;

  #pragma unroll 1
  for (int e = tid; e < 4*TPOS*8; e += 256){
    int pos = e >> 3, ch = e & 7;
    int row = pos / TPOS, col = pos % TPOS;
    int gy = r0 - 1 + row, gx = c0 - 1 + col;
    uint4 v = {0u,0u,0u,0u};
    if (gy >= 0 && gy < H_ && gx >= 0 && gx < W_)
      v = *(const uint4*)&ut[((size_t)b*HW_ + (size_t)gy*W_ + gx)*64 + ch*8];
    *(uint4*)&tile[pos*LSTR + ch*8] = v;
  }
  __syncthreads();

  int wave = tid >> 6, lane = tid & 63;
  int quad = lane >> 4, l15 = lane & 15;
  int cobase = (wave & 1)*32;
  int prow = wave >> 1;

  f32x4 acc[2][4];
  #pragma unroll
  for (int mt = 0; mt < 2; ++mt)
    #pragma unroll
    for (int nt = 0; nt < 4; ++nt)
      acc[mt][nt] = (f32x4){0.f,0.f,0.f,0.f};

  const unsigned short* Ap[2];
  #pragma unroll
  for (int mt = 0; mt < 2; ++mt)
    Ap[mt] = Asw + ((size_t)(((wave&1)*2 + mt)*18)*64 + lane)*8;

  int bbase = (prow*TPOS + l15)*LSTR + quad*8;

  #pragma unroll
  for (int tap = 0; tap < 9; ++tap){
    const int sh = (tap/3)*TPOS + (tap%3);
    #pragma unroll
    for (int cc = 0; cc < 2; ++cc){
      int kc = tap*2 + cc;
      bf16x8 a[2], bb[4];
      #pragma unroll
      for (int mt = 0; mt < 2; ++mt)
        a[mt] = *(const bf16x8*)(Ap[mt] + (size_t)kc*512);
      int boff = bbase + sh*LSTR + cc*32;
      #pragma unroll
      for (int nt = 0; nt < 4; ++nt)
        bb[nt] = *(const bf16x8*)&tile[boff + nt*16*LSTR];
      #pragma unroll
      for (int mt = 0; mt < 2; ++mt)
        #pragma unroll
        for (int nt = 0; nt < 4; ++nt)
          acc[mt][nt] = __builtin_amdgcn_mfma_f32_16x16x32_bf16(
              a[mt], bb[nt], acc[mt][nt], 0, 0, 0);
    }
  }

  int gy = r0 + prow;
  #pragma unroll
  for (int mt = 0; mt < 2; ++mt){
    int co4 = cobase + mt*16 + quad*4;
    f32x4 bs = *(const f32x4*)&bias[co4];
    #pragma unroll
    for (int nt = 0; nt < 4; ++nt){
      int gx = c0 + nt*16 + l15;
      size_t gpix = (size_t)gy*W_ + gx;
      float* yo = out + ((size_t)b*64 + co4)*HW_ + gpix;
      f32x4 v = acc[mt][nt] + bs;
      float r0v = v.x + yo[(size_t)0*HW_];
      float r1v = v.y + yo[(size_t)1*HW_];
      float r2v = v.z + yo[(size_t)2*HW_];
      float r3v = v.w + yo[(size_t)3*HW_];
      yo[(size_t)0*HW_] = r0v > 0.f ? r0v : 0.f;
      yo[(size_t)1*HW_] = r1v > 0.f ? r1v : 0.f;
      yo[(size_t)2*HW_] = r2v > 0.f ? r2v : 0.f;
      yo[(size_t)3*HW_] = r3v > 0.f ? r3v : 0.f;
    }
  }
}

// ---------------- gather + 2 MLPs (layer1 via MFMA) + softmax + weighted sum + scatter ----------
// MLP1 as GEMM per point: D[m=16][n=144] = featsB[16][160] @ W1cat[160][144] (bf16 MFMA),
// m = neighbor k (9 used), n = concat(d_w1 cols | r_w1 cols) (130 used), K = feature dim (131 used).
#define FBSTR 176   // featsB row stride in bf16 (160 data + 16 pad; keeps 16B align + bank spread)

__global__ __launch_bounds__(256) void attn_kernel(
    const unsigned short* __restrict__ d0t, const unsigned short* __restrict__ r0t,
    const int* __restrict__ pc_idx, const int* __restrict__ nbrs_idx,
    const float* __restrict__ disp,
    const unsigned short* __restrict__ Bmlp,   // swizzled [dw1|rw1] B-frags (45*64*8 bf16)
    const float* __restrict__ db2v, const float* __restrict__ dw2,
    const float* __restrict__ rb2v, const float* __restrict__ rw2,
    const float* __restrict__ dbias, const float* __restrict__ rbias,
    unsigned short* __restrict__ u_d, unsigned short* __restrict__ u_r)
{
  __shared__ float feats[9][64];                 // raw gathered dnn (fp32)
  __shared__ unsigned short featsB[16][FBSTR];   // bf16 MFMA A operand, zero-padded
  __shared__ float ds_s[64], rs_s[64];
  __shared__ float hbuf[2][9][66];
  __shared__ float part2[2][9][8];
  __shared__ float logitS[2][9];
  __shared__ float attnS[2][9];
  __shared__ int nbrS[9];

  int n = blockIdx.x, b = blockIdx.y;
  int tid = threadIdx.x;
  int s = pc_idx[(size_t)b * Ns_ + n];

  // phase 0: zero featsB (pad rows/cols must be clean for MFMA), load neighbor indices
  {
    uint4 z = {0u,0u,0u,0u};
    uint4* fb = (uint4*)&featsB[0][0];
    for (int e = tid; e < 16*FBSTR/8; e += 256) fb[e] = z;
  }
  if (tid < 9) nbrS[tid] = nbrs_idx[((size_t)b * Ns_ + n) * K_ + tid];
  __syncthreads();

  // phase 1: vectorized gather (uint4 = 8 bf16 per lane) + disp into featsB
  if (tid < 88){
    int k = tid >> 3, p = tid & 7, c0p = p << 3;
    const unsigned short* srcp =
        (k < 9)  ? &d0t[((size_t)b*HW_ + (size_t)nbrS[k])*64 + c0p] :
        (k == 9) ? &d0t[((size_t)b*HW_ + (size_t)s)*64 + c0p]
                 : &r0t[((size_t)b*HW_ + (size_t)s)*64 + c0p];
    uint4 v = *(const uint4*)srcp;
    const unsigned short* us = (const unsigned short*)&v;
    float* dst = (k < 9) ? &feats[k][c0p] : ((k == 9) ? &ds_s[c0p] : &rs_s[c0p]);
    #pragma unroll
    for (int t2 = 0; t2 < 8; ++t2) dst[t2] = b2f(us[t2]);
  }
  if (tid >= 128 && tid < 155){
    int t2 = tid - 128, m = t2 / 9, k = t2 % 9;
    featsB[k][128 + m] = f2b(disp[(((size_t)b * 3 + m) * Ns_ + n) * K_ + k]);
  }
  __syncthreads();

  // phase 2: build bf16 feature rows: [dnn-ds | dnn-rs | disp | 0-pad]
  for (int e = tid; e < 9*64; e += 256){
    int k = e >> 6, c = e & 63;
    float dnn = feats[k][c];
    featsB[k][c]      = f2b(dnn - ds_s[c]);
    featsB[k][64 + c] = f2b(dnn - rs_s[c]);
  }
  __syncthreads();

  // phase 3: MLP layer-1 via MFMA. 4 waves split the 9 n-tiles.
  {
    int wave = tid >> 6, lane = tid & 63, quad = lane >> 4, l15 = lane & 15;
    bf16x8 afr[5];
    #pragma unroll
    for (int ks = 0; ks < 5; ++ks)
      afr[ks] = *(const bf16x8*)&featsB[l15][ks*32 + quad*8];
    for (int nt = wave; nt < 9; nt += 4){
      f32x4 acc = (f32x4){0.f,0.f,0.f,0.f};
      const unsigned short* bp = Bmlp + ((size_t)nt*5*64 + lane)*8;
      #pragma unroll
      for (int ks = 0; ks < 5; ++ks){
        bf16x8 bfr = *(const bf16x8*)(bp + (size_t)ks*512);
        acc = __builtin_amdgcn_mfma_f32_16x16x32_bf16(afr[ks], bfr, acc, 0, 0, 0);
      }
      int jq = nt*16 + l15;
      if (jq < 2*Dh_){
        int mlp = (jq >= Dh_) ? 1 : 0;
        int j = jq - mlp*Dh_;
        #pragma unroll
        for (int r = 0; r < 4; ++r){
          int m = quad*4 + r;
          if (m < 9){
            float h = acc[r];
            hbuf[mlp][m][j] = h > 0.f ? h : 0.2f*h;   // leaky relu 0.2
          }
        }
      }
    }
  }
  __syncthreads();

  // phase 4: layer-2 partial dots (8-way split of the 65-dot)
  if (tid < 144){
    int mlp = tid / 72, r2 = tid % 72, k = r2 >> 3, p = r2 & 7;
    const float* w2 = mlp ? rw2 : dw2;
    float sm = 0.f;
    for (int j = p; j < Dh_; j += 8) sm += hbuf[mlp][k][j] * w2[j];
    part2[mlp][k][p] = sm;
  }
  __syncthreads();

  if (tid < 18){
    int mlp = tid / 9, k = tid % 9;
    float l = (mlp ? rb2v : db2v)[0];
    #pragma unroll
    for (int p = 0; p < 8; ++p) l += part2[mlp][k][p];
    logitS[mlp][k] = l;
  }
  __syncthreads();

  if (tid < 2){
    float m = logitS[tid][0];
    for (int k = 1; k < 9; ++k) m = fmaxf(m, logitS[tid][k]);
    float e[9], sum = 0.f;
    for (int k = 0; k < 9; ++k){ e[k] = __expf(logitS[tid][k] - m); sum += e[k]; }
    float inv = 1.f / sum;
    for (int k = 0; k < 9; ++k) attnS[tid][k] = e[k] * inv;
  }
  __syncthreads();

  // phase 5: weighted sum of raw dnn + scatter (channel 0 replaces, others add residual)
  if (tid < 128){
    int mlp = tid >> 6, c = tid & 63;
    float f = (mlp ? rbias : dbias)[c];
    #pragma unroll
    for (int k = 0; k < 9; ++k)
      f += attnS[mlp][k] * feats[k][c];
    float base = (c == 0) ? 0.f : (mlp ? rs_s[c] : ds_s[c]);
    unsigned short* u = mlp ? u_r : u_d;
    u[((size_t)b * HW_ + (size_t)s) * 64 + c] = f2b(base + f);
  }
}

// ---------------- launch ----------------
extern "C" void kernel_launch(void* const* d_in, const int* in_sizes, int n_in,
                              void* d_out, int out_size, void* d_ws, size_t ws_size,
                              hipStream_t stream)
{
  (void)in_sizes; (void)n_in; (void)out_size; (void)ws_size;

  const float* rgb       = (const float*)d_in[0];
  const float* sdepth    = (const float*)d_in[1];
  const int*   pc_idx    = (const int*)d_in[2];
  const int*   nbrs_idx  = (const int*)d_in[3];
  const float* nbrs_disp = (const float*)d_in[4];

  WPtrs wp;
  wp.w[0] = (const float*)d_in[5];   // d_conv0_w
  wp.w[1] = (const float*)d_in[7];   // d_conv1_w
  wp.w[2] = (const float*)d_in[9];   // d_conv2_w
  wp.w[3] = (const float*)d_in[11];  // r_conv0_w
  wp.w[4] = (const float*)d_in[13];  // r_conv1_w
  wp.w[5] = (const float*)d_in[15];  // r_conv2_w
  const float* d_conv0_b = (const float*)d_in[6];
  const float* d_conv1_b = (const float*)d_in[8];
  const float* d_conv2_b = (const float*)d_in[10];
  const float* r_conv0_b = (const float*)d_in[12];
  const float* r_conv1_b = (const float*)d_in[14];
  const float* r_conv2_b = (const float*)d_in[16];
  const float* d_w1 = (const float*)d_in[17];
  const float* d_b2 = (const float*)d_in[20];
  const float* d_w2 = (const float*)d_in[19];
  const float* r_w1 = (const float*)d_in[21];
  const float* r_w2 = (const float*)d_in[23];
  const float* r_b2 = (const float*)d_in[24];
  const float* d_bias = (const float*)d_in[25];
  const float* r_bias = (const float*)d_in[26];

  char* ws = (char*)d_ws;
  const size_t TSZ = (size_t)B_ * HW_ * 64 * 2;   // one transposed bf16 tensor
  unsigned short* u_d = (unsigned short*)(ws + 0*TSZ);
  unsigned short* u_r = (unsigned short*)(ws + 1*TSZ);
  unsigned short* d0t = (unsigned short*)(ws + 2*TSZ);
  unsigned short* r0t = (unsigned short*)(ws + 3*TSZ);
  unsigned short* Asw = (unsigned short*)(ws + 4*TSZ);
  const size_t CONV_STRIDE = 4*18*64*8;           // 36864 elems per conv
  unsigned short* Bmlp = Asw + 6*CONV_STRIDE;     // 45*64*8 = 23040 elems after convs

  prep_w<<<432, 64, 0, stream>>>(wp, Asw);
  prep_wmlp<<<45, 64, 0, stream>>>(d_w1, r_w1, Bmlp);

  float* out = (float*)d_out;
  const size_t OUTSZ = (size_t)B_ * 64 * HW_;

  dim3 cgrid(W_/64, H_/2, B_);
  conv01_mfma<<<cgrid, 256, 0, stream>>>(sdepth, Asw + 0*CONV_STRIDE,
      d_conv0_b, d_conv1_b, d0t, u_d, out);
  conv01_mfma<<<cgrid, 256, 0, stream>>>(rgb,    Asw + 3*CONV_STRIDE,
      r_conv0_b, r_conv1_b, r0t, u_r, out + OUTSZ);

  attn_kernel<<<dim3(Ns_, B_), 256, 0, stream>>>(
      d0t, r0t, pc_idx, nbrs_idx, nbrs_disp,
      Bmlp,
      d_b2, d_w2, r_b2, r_w2,
      d_bias, r_bias,
      u_d, u_r);

  conv2_mfma<<<cgrid, 256, 0, stream>>>(u_d, Asw + 2*CONV_STRIDE, d_conv2_b, out);
  conv2_mfma<<<cgrid, 256, 0, stream>>>(u_r, Asw + 5*CONV_STRIDE, r_conv2_b, out + OUTSZ);
}

// Round 2
// 1371.996 us; speedup vs baseline: 1.3025x; 1.3025x over previous
//
#include <hip/hip_runtime.h>

#define H_ 256
#define W_ 1216
#define HW_ (H_*W_)
#define B_ 2
#define Ns_ 20000
#define K_ 9
#define D_ 131
#define Dh_ 65

#define TPOS 66      // positions per tile row (64 + 2 halo)

typedef __attribute__((ext_vector_type(8))) short bf16x8;
typedef __attribute__((ext_vector_type(4))) float f32x4;

__device__ __forceinline__ float b2f(unsigned short u){
  union { unsigned int i; float f; } v; v.i = ((unsigned int)u) << 16; return v.f;
}
__device__ __forceinline__ unsigned short f2b(float f){
  union { float f; unsigned int i; } v; v.f = f;
  unsigned int r = (v.i + 0x7FFFu + ((v.i >> 16) & 1u)) >> 16;
  return (unsigned short)r;
}

// ---------------- weight swizzle: fp32 (C,Cin,3,3) -> bf16 MFMA A-frag order ----------------
// Layout: [conv(6)][mtile(4)][kc(18)][lane(64)][j(8)]; k = kc*32 + quad*8 + j; tap=k>>6, cin=k&63
struct WPtrs { const float* w[6]; };

__global__ void prep_w(WPtrs wp, unsigned short* __restrict__ Asw){
  int blk = blockIdx.x;                 // 6*4*18 = 432
  int c = blk / 72, rem = blk % 72, mt = rem / 18, kc = rem % 18;
  int lane = threadIdx.x;               // 64
  const float* w = wp.w[c];
  int co = mt*16 + (lane & 15);
  int kb = kc*32 + (lane >> 4)*8;
  unsigned short* dst = Asw + ((size_t)blk*64 + lane)*8;
  #pragma unroll
  for (int j = 0; j < 8; ++j){
    int k = kb + j, tap = k >> 6, cin = k & 63;
    dst[j] = f2b(w[((size_t)co*64 + cin)*9 + tap]);
  }
}

// ---------------- MLP layer-1 weight swizzle: [dw1|rw1] (131x130) -> bf16 MFMA B-frag order ----
__global__ void prep_wmlp(const float* __restrict__ dw1, const float* __restrict__ rw1,
                          unsigned short* __restrict__ Bm){
  int blk = blockIdx.x;                 // 45
  int nt = blk / 5, ks = blk % 5;
  int lane = threadIdx.x;               // 64
  int col = nt*16 + (lane & 15);
  int kb  = ks*32 + (lane >> 4)*8;
  unsigned short* dst = Bm + ((size_t)blk*64 + lane)*8;
  #pragma unroll
  for (int jj = 0; jj < 8; ++jj){
    int row = kb + jj;
    float v = 0.f;
    if (row < D_ && col < 2*Dh_)
      v = (col < Dh_) ? dw1[(size_t)row*Dh_ + col] : rw1[(size_t)row*Dh_ + (col - Dh_)];
    dst[jj] = f2b(v);
  }
}

// ---------------- transpose: fp32 NCHW -> bf16 (B,HW,64), coalesced both ways ----------------
// Block: 128 positions x 64 cin. LDS slot-XOR swizzle keeps all LDS phases conflict-free.
__global__ __launch_bounds__(256) void transpose_in(
    const float* __restrict__ x, unsigned short* __restrict__ xt)
{
  __shared__ unsigned short t[128*64];
  int tid = threadIdx.x, l = tid & 63, w = tid >> 6;
  int b = blockIdx.y;
  size_t p0 = (size_t)blockIdx.x * 128;
  int pos = (w & 1)*64 + l;
  const float* src = x + (size_t)b*64*HW_ + p0 + pos;
  #pragma unroll
  for (int it = 0; it < 4; ++it){
    int c8 = (w >> 1)*4 + it;   // cin group of 8
    union { unsigned short us[8]; uint4 v; } pk;
    #pragma unroll
    for (int j = 0; j < 8; ++j)
      pk.us[j] = f2b(src[(size_t)(c8*8 + j)*HW_]);
    *(uint4*)&t[pos*64 + ((c8 ^ (pos & 7)) << 3)] = pk.v;
  }
  __syncthreads();
  unsigned short* dst = xt + ((size_t)b*HW_ + p0)*64;
  #pragma unroll
  for (int it = 0; it < 4; ++it){
    int e = it*256 + tid;
    int pp = e >> 3, sl = e & 7;
    *(uint4*)&dst[(size_t)pp*64 + sl*8] =
        *(const uint4*)&t[pp*64 + ((sl ^ (pp & 7)) << 3)];
  }
}

// ---------------- fused conv0(relu)+conv1, implicit-GEMM MFMA ----------------
// xt bf16 (B,HW,64). y0t,u: bf16 (B,HW,64). y1out: fp32 NCHW (= d_out region).
__global__ __launch_bounds__(256,4) void conv01_mfma(
    const unsigned short* __restrict__ xt,
    const unsigned short* __restrict__ Asw,   // conv0 at +0, conv1 at +36864
    const float* __restrict__ b0, const float* __restrict__ b1,
    unsigned short* __restrict__ y0t, unsigned short* __restrict__ u,
    float* __restrict__ y1out)
{
  __shared__ unsigned short tile[4*TPOS*64];
  int tid = threadIdx.x;
  int c0 = blockIdx.x*64, r0 = blockIdx.y*2, b = blockIdx.z;

  // stage 4 rows x 66 cols x 64 cin from (HW,64) bf16; slot-XOR swizzled
  for (int e = tid; e < 4*TPOS*8; e += 256){
    int pos = e >> 3, ch = e & 7;
    int row = pos / TPOS, col = pos - row*TPOS;
    int gy = r0 - 1 + row, gx = c0 - 1 + col;
    uint4 v = {0u,0u,0u,0u};
    if (gy >= 0 && gy < H_ && gx >= 0 && gx < W_)
      v = *(const uint4*)&xt[((size_t)b*HW_ + (size_t)gy*W_ + gx)*64 + ch*8];
    *(uint4*)&tile[pos*64 + ((ch ^ (pos & 7)) << 3)] = v;
  }
  __syncthreads();

  int wave = tid >> 6, lane = tid & 63;
  int quad = lane >> 4, l15 = lane & 15;
  int cobase = (wave & 1)*32;    // wave covers co [cobase, cobase+32)
  int prow = wave >> 1;          // wave covers row r0+prow, cols 0..63

  f32x4 acc[2][2][4];
  #pragma unroll
  for (int cv = 0; cv < 2; ++cv)
    #pragma unroll
    for (int mt = 0; mt < 2; ++mt)
      #pragma unroll
      for (int nt = 0; nt < 4; ++nt)
        acc[cv][mt][nt] = (f32x4){0.f,0.f,0.f,0.f};

  const unsigned short* Ap[2][2];
  #pragma unroll
  for (int cv = 0; cv < 2; ++cv)
    #pragma unroll
    for (int mt = 0; mt < 2; ++mt)
      Ap[cv][mt] = Asw + ((size_t)((cv*4 + (wave&1)*2 + mt)*18)*64 + lane)*8;

  #pragma unroll
  for (int tap = 0; tap < 9; ++tap){
    int pbase = (prow + tap/3)*TPOS + l15 + (tap%3);
    int pk = pbase & 7;
    #pragma unroll
    for (int cc = 0; cc < 2; ++cc){
      int kc = tap*2 + cc;
      int sl = ((quad + 4*cc) ^ pk) << 3;
      bf16x8 a[2][2], bb[4];
      #pragma unroll
      for (int cv = 0; cv < 2; ++cv)
        #pragma unroll
        for (int mt = 0; mt < 2; ++mt)
          a[cv][mt] = *(const bf16x8*)(Ap[cv][mt] + (size_t)kc*512);
      #pragma unroll
      for (int nt = 0; nt < 4; ++nt)
        bb[nt] = *(const bf16x8*)&tile[(pbase + nt*16)*64 + sl];
      #pragma unroll
      for (int cv = 0; cv < 2; ++cv)
        #pragma unroll
        for (int mt = 0; mt < 2; ++mt)
          #pragma unroll
          for (int nt = 0; nt < 4; ++nt)
            acc[cv][mt][nt] = __builtin_amdgcn_mfma_f32_16x16x32_bf16(
                a[cv][mt], bb[nt], acc[cv][mt][nt], 0, 0, 0);
    }
  }

  int gy = r0 + prow;
  #pragma unroll
  for (int mt = 0; mt < 2; ++mt){
    int co4 = cobase + mt*16 + quad*4;
    f32x4 bias0 = *(const f32x4*)&b0[co4];
    f32x4 bias1 = *(const f32x4*)&b1[co4];
    #pragma unroll
    for (int nt = 0; nt < 4; ++nt){
      int gx = c0 + nt*16 + l15;
      size_t gpix = (size_t)gy*W_ + gx;
      f32x4 v0 = acc[0][mt][nt] + bias0;
      ushort4 q;
      q.x = f2b(fmaxf(v0.x,0.f)); q.y = f2b(fmaxf(v0.y,0.f));
      q.z = f2b(fmaxf(v0.z,0.f)); q.w = f2b(fmaxf(v0.w,0.f));
      size_t toff = ((size_t)b*HW_ + gpix)*64 + co4;
      *(ushort4*)&y0t[toff] = q;
      *(ushort4*)&u[toff]   = q;
      f32x4 v1 = acc[1][mt][nt] + bias1;
      float* yo = y1out + ((size_t)b*64 + co4)*HW_ + gpix;
      yo[(size_t)0*HW_] = v1.x; yo[(size_t)1*HW_] = v1.y;
      yo[(size_t)2*HW_] = v1.z; yo[(size_t)3*HW_] = v1.w;
    }
  }
}

// ---------------- conv2 + add(out-resident y1) + relu, implicit-GEMM MFMA ----------------
__global__ __launch_bounds__(256,4) void conv2_mfma(
    const unsigned short* __restrict__ ut,    // (B,HW,64) bf16
    const unsigned short* __restrict__ Asw,   // this conv's swizzled base
    const float* __restrict__ bias,
    float* __restrict__ out)                  // fp32 NCHW; holds y1; read-add-write
{
  __shared__ unsigned short tile[4*TPOS*64];
  int tid = threadIdx.x;
  int c0 = blockIdx.x*64, r0 = blockIdx.y*2, b = blockIdx.z;

  for (int e = tid; e < 4*TPOS*8; e += 256){
    int pos = e >> 3, ch = e & 7;
    int row = pos / TPOS, col = pos - row*TPOS;
    int gy = r0 - 1 + row, gx = c0 - 1 + col;
    uint4 v = {0u,0u,0u,0u};
    if (gy >= 0 && gy < H_ && gx >= 0 && gx < W_)
      v = *(const uint4*)&ut[((size_t)b*HW_ + (size_t)gy*W_ + gx)*64 + ch*8];
    *(uint4*)&tile[pos*64 + ((ch ^ (pos & 7)) << 3)] = v;
  }
  __syncthreads();

  int wave = tid >> 6, lane = tid & 63;
  int quad = lane >> 4, l15 = lane & 15;
  int cobase = (wave & 1)*32;
  int prow = wave >> 1;

  f32x4 acc[2][4];
  #pragma unroll
  for (int mt = 0; mt < 2; ++mt)
    #pragma unroll
    for (int nt = 0; nt < 4; ++nt)
      acc[mt][nt] = (f32x4){0.f,0.f,0.f,0.f};

  const unsigned short* Ap[2];
  #pragma unroll
  for (int mt = 0; mt < 2; ++mt)
    Ap[mt] = Asw + ((size_t)(((wave&1)*2 + mt)*18)*64 + lane)*8;

  #pragma unroll
  for (int tap = 0; tap < 9; ++tap){
    int pbase = (prow + tap/3)*TPOS + l15 + (tap%3);
    int pk = pbase & 7;
    #pragma unroll
    for (int cc = 0; cc < 2; ++cc){
      int kc = tap*2 + cc;
      int sl = ((quad + 4*cc) ^ pk) << 3;
      bf16x8 a[2], bb[4];
      #pragma unroll
      for (int mt = 0; mt < 2; ++mt)
        a[mt] = *(const bf16x8*)(Ap[mt] + (size_t)kc*512);
      #pragma unroll
      for (int nt = 0; nt < 4; ++nt)
        bb[nt] = *(const bf16x8*)&tile[(pbase + nt*16)*64 + sl];
      #pragma unroll
      for (int mt = 0; mt < 2; ++mt)
        #pragma unroll
        for (int nt = 0; nt < 4; ++nt)
          acc[mt][nt] = __builtin_amdgcn_mfma_f32_16x16x32_bf16(
              a[mt], bb[nt], acc[mt][nt], 0, 0, 0);
    }
  }

  int gy = r0 + prow;
  #pragma unroll
  for (int mt = 0; mt < 2; ++mt){
    int co4 = cobase + mt*16 + quad*4;
    f32x4 bs = *(const f32x4*)&bias[co4];
    #pragma unroll
    for (int nt = 0; nt < 4; ++nt){
      int gx = c0 + nt*16 + l15;
      size_t gpix = (size_t)gy*W_ + gx;
      float* yo = out + ((size_t)b*64 + co4)*HW_ + gpix;
      f32x4 v = acc[mt][nt] + bs;
      float r0v = v.x + yo[(size_t)0*HW_];
      float r1v = v.y + yo[(size_t)1*HW_];
      float r2v = v.z + yo[(size_t)2*HW_];
      float r3v = v.w + yo[(size_t)3*HW_];
      yo[(size_t)0*HW_] = r0v > 0.f ? r0v : 0.f;
      yo[(size_t)1*HW_] = r1v > 0.f ? r1v : 0.f;
      yo[(size_t)2*HW_] = r2v > 0.f ? r2v : 0.f;
      yo[(size_t)3*HW_] = r3v > 0.f ? r3v : 0.f;
    }
  }
}

// ---------------- gather + 2 MLPs (layer1 via MFMA) + softmax + weighted sum + scatter ----------
#define FBSTR 176   // featsB row stride in bf16 (160 data + 16 pad)

__global__ __launch_bounds__(256) void attn_kernel(
    const unsigned short* __restrict__ d0t, const unsigned short* __restrict__ r0t,
    const int* __restrict__ pc_idx, const int* __restrict__ nbrs_idx,
    const float* __restrict__ disp,
    const unsigned short* __restrict__ Bmlp,   // swizzled [dw1|rw1] B-frags (45*64*8 bf16)
    const float* __restrict__ db2v, const float* __restrict__ dw2,
    const float* __restrict__ rb2v, const float* __restrict__ rw2,
    const float* __restrict__ dbias, const float* __restrict__ rbias,
    unsigned short* __restrict__ u_d, unsigned short* __restrict__ u_r)
{
  __shared__ float feats[9][64];                 // raw gathered dnn (fp32)
  __shared__ unsigned short featsB[16][FBSTR];   // bf16 MFMA A operand, zero-padded
  __shared__ float ds_s[64], rs_s[64];
  __shared__ float hbuf[2][9][66];
  __shared__ float part2[2][9][8];
  __shared__ float logitS[2][9];
  __shared__ float attnS[2][9];
  __shared__ int nbrS[9];

  int n = blockIdx.x, b = blockIdx.y;
  int tid = threadIdx.x;
  int s = pc_idx[(size_t)b * Ns_ + n];

  // phase 0: zero featsB, load neighbor indices
  {
    uint4 z = {0u,0u,0u,0u};
    uint4* fb = (uint4*)&featsB[0][0];
    for (int e = tid; e < 16*FBSTR/8; e += 256) fb[e] = z;
  }
  if (tid < 9) nbrS[tid] = nbrs_idx[((size_t)b * Ns_ + n) * K_ + tid];
  __syncthreads();

  // phase 1: vectorized gather (uint4 = 8 bf16 per lane) + disp
  if (tid < 88){
    int k = tid >> 3, p = tid & 7, c0p = p << 3;
    const unsigned short* srcp =
        (k < 9)  ? &d0t[((size_t)b*HW_ + (size_t)nbrS[k])*64 + c0p] :
        (k == 9) ? &d0t[((size_t)b*HW_ + (size_t)s)*64 + c0p]
                 : &r0t[((size_t)b*HW_ + (size_t)s)*64 + c0p];
    uint4 v = *(const uint4*)srcp;
    const unsigned short* us = (const unsigned short*)&v;
    float* dst = (k < 9) ? &feats[k][c0p] : ((k == 9) ? &ds_s[c0p] : &rs_s[c0p]);
    #pragma unroll
    for (int t2 = 0; t2 < 8; ++t2) dst[t2] = b2f(us[t2]);
  }
  if (tid >= 128 && tid < 155){
    int t2 = tid - 128, m = t2 / 9, k = t2 % 9;
    featsB[k][128 + m] = f2b(disp[(((size_t)b * 3 + m) * Ns_ + n) * K_ + k]);
  }
  __syncthreads();

  // phase 2: build bf16 feature rows: [dnn-ds | dnn-rs | disp | 0-pad]
  for (int e = tid; e < 9*64; e += 256){
    int k = e >> 6, c = e & 63;
    float dnn = feats[k][c];
    featsB[k][c]      = f2b(dnn - ds_s[c]);
    featsB[k][64 + c] = f2b(dnn - rs_s[c]);
  }
  __syncthreads();

  // phase 3: MLP layer-1 via MFMA. 4 waves split the 9 n-tiles.
  {
    int wave = tid >> 6, lane = tid & 63, quad = lane >> 4, l15 = lane & 15;
    bf16x8 afr[5];
    #pragma unroll
    for (int ks = 0; ks < 5; ++ks)
      afr[ks] = *(const bf16x8*)&featsB[l15][ks*32 + quad*8];
    for (int nt = wave; nt < 9; nt += 4){
      f32x4 acc = (f32x4){0.f,0.f,0.f,0.f};
      const unsigned short* bp = Bmlp + ((size_t)nt*5*64 + lane)*8;
      #pragma unroll
      for (int ks = 0; ks < 5; ++ks){
        bf16x8 bfr = *(const bf16x8*)(bp + (size_t)ks*512);
        acc = __builtin_amdgcn_mfma_f32_16x16x32_bf16(afr[ks], bfr, acc, 0, 0, 0);
      }
      int jq = nt*16 + l15;
      if (jq < 2*Dh_){
        int mlp = (jq >= Dh_) ? 1 : 0;
        int j = jq - mlp*Dh_;
        #pragma unroll
        for (int r = 0; r < 4; ++r){
          int m = quad*4 + r;
          if (m < 9){
            float h = acc[r];
            hbuf[mlp][m][j] = h > 0.f ? h : 0.2f*h;   // leaky relu 0.2
          }
        }
      }
    }
  }
  __syncthreads();

  // phase 4: layer-2 partial dots (8-way split of the 65-dot)
  if (tid < 144){
    int mlp = tid / 72, r2 = tid % 72, k = r2 >> 3, p = r2 & 7;
    const float* w2 = mlp ? rw2 : dw2;
    float sm = 0.f;
    for (int j = p; j < Dh_; j += 8) sm += hbuf[mlp][k][j] * w2[j];
    part2[mlp][k][p] = sm;
  }
  __syncthreads();

  if (tid < 18){
    int mlp = tid / 9, k = tid % 9;
    float l = (mlp ? rb2v : db2v)[0];
    #pragma unroll
    for (int p = 0; p < 8; ++p) l += part2[mlp][k][p];
    logitS[mlp][k] = l;
  }
  __syncthreads();

  if (tid < 2){
    float m = logitS[tid][0];
    for (int k = 1; k < 9; ++k) m = fmaxf(m, logitS[tid][k]);
    float e[9], sum = 0.f;
    for (int k = 0; k < 9; ++k){ e[k] = __expf(logitS[tid][k] - m); sum += e[k]; }
    float inv = 1.f / sum;
    for (int k = 0; k < 9; ++k) attnS[tid][k] = e[k] * inv;
  }
  __syncthreads();

  // phase 5: weighted sum of raw dnn + scatter (channel 0 replaces, others add residual)
  if (tid < 128){
    int mlp = tid >> 6, c = tid & 63;
    float f = (mlp ? rbias : dbias)[c];
    #pragma unroll
    for (int k = 0; k < 9; ++k)
      f += attnS[mlp][k] * feats[k][c];
    float base = (c == 0) ? 0.f : (mlp ? rs_s[c] : ds_s[c]);
    unsigned short* u = mlp ? u_r : u_d;
    u[((size_t)b * HW_ + (size_t)s) * 64 + c] = f2b(base + f);
  }
}

// ---------------- launch ----------------
extern "C" void kernel_launch(void* const* d_in, const int* in_sizes, int n_in,
                              void* d_out, int out_size, void* d_ws, size_t ws_size,
                              hipStream_t stream)
{
  (void)in_sizes; (void)n_in; (void)out_size; (void)ws_size;

  const float* rgb       = (const float*)d_in[0];
  const float* sdepth    = (const float*)d_in[1];
  const int*   pc_idx    = (const int*)d_in[2];
  const int*   nbrs_idx  = (const int*)d_in[3];
  const float* nbrs_disp = (const float*)d_in[4];

  WPtrs wp;
  wp.w[0] = (const float*)d_in[5];   // d_conv0_w
  wp.w[1] = (const float*)d_in[7];   // d_conv1_w
  wp.w[2] = (const float*)d_in[9];   // d_conv2_w
  wp.w[3] = (const float*)d_in[11];  // r_conv0_w
  wp.w[4] = (const float*)d_in[13];  // r_conv1_w
  wp.w[5] = (const float*)d_in[15];  // r_conv2_w
  const float* d_conv0_b = (const float*)d_in[6];
  const float* d_conv1_b = (const float*)d_in[8];
  const float* d_conv2_b = (const float*)d_in[10];
  const float* r_conv0_b = (const float*)d_in[12];
  const float* r_conv1_b = (const float*)d_in[14];
  const float* r_conv2_b = (const float*)d_in[16];
  const float* d_w1 = (const float*)d_in[17];
  const float* d_w2 = (const float*)d_in[19];
  const float* d_b2 = (const float*)d_in[20];
  const float* r_w1 = (const float*)d_in[21];
  const float* r_w2 = (const float*)d_in[23];
  const float* r_b2 = (const float*)d_in[24];
  const float* d_bias = (const float*)d_in[25];
  const float* r_bias = (const float*)d_in[26];

  char* ws = (char*)d_ws;
  const size_t TSZ = (size_t)B_ * HW_ * 64 * 2;   // one transposed bf16 tensor
  unsigned short* u_d = (unsigned short*)(ws + 0*TSZ);
  unsigned short* u_r = (unsigned short*)(ws + 1*TSZ);
  unsigned short* d0t = (unsigned short*)(ws + 2*TSZ);
  unsigned short* r0t = (unsigned short*)(ws + 3*TSZ);
  unsigned short* xt  = (unsigned short*)(ws + 4*TSZ);   // transposed input (reused d then r)
  unsigned short* Asw = (unsigned short*)(ws + 5*TSZ);
  const size_t CONV_STRIDE = 4*18*64*8;           // 36864 elems per conv
  unsigned short* Bmlp = Asw + 6*CONV_STRIDE;     // 45*64*8 = 23040 elems after convs

  prep_w<<<432, 64, 0, stream>>>(wp, Asw);
  prep_wmlp<<<45, 64, 0, stream>>>(d_w1, r_w1, Bmlp);

  float* out = (float*)d_out;
  const size_t OUTSZ = (size_t)B_ * 64 * HW_;

  dim3 cgrid(W_/64, H_/2, B_);
  dim3 tgrid(HW_/128, B_);

  transpose_in<<<tgrid, 256, 0, stream>>>(sdepth, xt);
  conv01_mfma<<<cgrid, 256, 0, stream>>>(xt, Asw + 0*CONV_STRIDE,
      d_conv0_b, d_conv1_b, d0t, u_d, out);
  transpose_in<<<tgrid, 256, 0, stream>>>(rgb, xt);
  conv01_mfma<<<cgrid, 256, 0, stream>>>(xt, Asw + 3*CONV_STRIDE,
      r_conv0_b, r_conv1_b, r0t, u_r, out + OUTSZ);

  attn_kernel<<<dim3(Ns_, B_), 256, 0, stream>>>(
      d0t, r0t, pc_idx, nbrs_idx, nbrs_disp,
      Bmlp,
      d_b2, d_w2, r_b2, r_w2,
      d_bias, r_bias,
      u_d, u_r);

  conv2_mfma<<<cgrid, 256, 0, stream>>>(u_d, Asw + 2*CONV_STRIDE, d_conv2_b, out);
  conv2_mfma<<<cgrid, 256, 0, stream>>>(u_r, Asw + 5*CONV_STRIDE, r_conv2_b, out + OUTSZ);
}

// Round 3
// 1363.950 us; speedup vs baseline: 1.3102x; 1.0059x over previous
//
#include <hip/hip_runtime.h>

#define H_ 256
#define W_ 1216
#define HW_ (H_*W_)
#define B_ 2
#define Ns_ 20000
#define K_ 9
#define D_ 131
#define Dh_ 65

#define TPOS 66      // positions per tile row (64 + 2 halo)

typedef __attribute__((ext_vector_type(8))) short bf16x8;
typedef __attribute__((ext_vector_type(4))) float f32x4;

__device__ __forceinline__ float b2f(unsigned short u){
  union { unsigned int i; float f; } v; v.i = ((unsigned int)u) << 16; return v.f;
}
__device__ __forceinline__ unsigned short f2b(float f){
  union { float f; unsigned int i; } v; v.f = f;
  unsigned int r = (v.i + 0x7FFFu + ((v.i >> 16) & 1u)) >> 16;
  return (unsigned short)r;
}

// ---------------- weight swizzle: fp32 (C,Cin,3,3) -> bf16 MFMA A-frag order ----------------
// Layout: [conv(6)][mtile(4)][kc(18)][lane(64)][j(8)]; k = kc*32 + quad*8 + j; tap=k>>6, cin=k&63
struct WPtrs { const float* w[6]; };

__global__ void prep_w(WPtrs wp, unsigned short* __restrict__ Asw){
  int blk = blockIdx.x;                 // 6*4*18 = 432
  int c = blk / 72, rem = blk % 72, mt = rem / 18, kc = rem % 18;
  int lane = threadIdx.x;               // 64
  const float* w = wp.w[c];
  int co = mt*16 + (lane & 15);
  int kb = kc*32 + (lane >> 4)*8;
  unsigned short* dst = Asw + ((size_t)blk*64 + lane)*8;
  #pragma unroll
  for (int j = 0; j < 8; ++j){
    int k = kb + j, tap = k >> 6, cin = k & 63;
    dst[j] = f2b(w[((size_t)co*64 + cin)*9 + tap]);
  }
}

// ---------------- MLP layer-1 weight swizzle: [dw1|rw1] (131x130) -> bf16 MFMA B-frag order ----
__global__ void prep_wmlp(const float* __restrict__ dw1, const float* __restrict__ rw1,
                          unsigned short* __restrict__ Bm){
  int blk = blockIdx.x;                 // 45
  int nt = blk / 5, ks = blk % 5;
  int lane = threadIdx.x;               // 64
  int col = nt*16 + (lane & 15);
  int kb  = ks*32 + (lane >> 4)*8;
  unsigned short* dst = Bm + ((size_t)blk*64 + lane)*8;
  #pragma unroll
  for (int jj = 0; jj < 8; ++jj){
    int row = kb + jj;
    float v = 0.f;
    if (row < D_ && col < 2*Dh_)
      v = (col < Dh_) ? dw1[(size_t)row*Dh_ + col] : rw1[(size_t)row*Dh_ + (col - Dh_)];
    dst[jj] = f2b(v);
  }
}

// ---------------- transpose: fp32 NCHW -> bf16 (B,HW,64), coalesced both ways ----------------
__global__ __launch_bounds__(256) void transpose_in(
    const float* __restrict__ x, unsigned short* __restrict__ xt)
{
  __shared__ unsigned short t[128*64];
  int tid = threadIdx.x, l = tid & 63, w = tid >> 6;
  int b = blockIdx.y;
  size_t p0 = (size_t)blockIdx.x * 128;
  int pos = (w & 1)*64 + l;
  const float* src = x + (size_t)b*64*HW_ + p0 + pos;
  #pragma unroll
  for (int it = 0; it < 4; ++it){
    int c8 = (w >> 1)*4 + it;   // cin group of 8
    union { unsigned short us[8]; uint4 v; } pk;
    #pragma unroll
    for (int j = 0; j < 8; ++j)
      pk.us[j] = f2b(src[(size_t)(c8*8 + j)*HW_]);
    *(uint4*)&t[pos*64 + ((c8 ^ (pos & 7)) << 3)] = pk.v;
  }
  __syncthreads();
  unsigned short* dst = xt + ((size_t)b*HW_ + p0)*64;
  #pragma unroll
  for (int it = 0; it < 4; ++it){
    int e = it*256 + tid;
    int pp = e >> 3, sl = e & 7;
    *(uint4*)&dst[(size_t)pp*64 + sl*8] =
        *(const uint4*)&t[pp*64 + ((sl ^ (pp & 7)) << 3)];
  }
}

// ---------------- fused conv0(relu)+conv1, implicit-GEMM MFMA ----------------
__global__ __launch_bounds__(256,4) void conv01_mfma(
    const unsigned short* __restrict__ xt,
    const unsigned short* __restrict__ Asw,   // conv0 at +0, conv1 at +36864
    const float* __restrict__ b0, const float* __restrict__ b1,
    unsigned short* __restrict__ y0t, unsigned short* __restrict__ u,
    float* __restrict__ y1out)
{
  __shared__ unsigned short tile[4*TPOS*64];
  int tid = threadIdx.x;
  int c0 = blockIdx.x*64, r0 = blockIdx.y*2, b = blockIdx.z;

  for (int e = tid; e < 4*TPOS*8; e += 256){
    int pos = e >> 3, ch = e & 7;
    int row = pos / TPOS, col = pos - row*TPOS;
    int gy = r0 - 1 + row, gx = c0 - 1 + col;
    uint4 v = {0u,0u,0u,0u};
    if (gy >= 0 && gy < H_ && gx >= 0 && gx < W_)
      v = *(const uint4*)&xt[((size_t)b*HW_ + (size_t)gy*W_ + gx)*64 + ch*8];
    *(uint4*)&tile[pos*64 + ((ch ^ (pos & 7)) << 3)] = v;
  }
  __syncthreads();

  int wave = tid >> 6, lane = tid & 63;
  int quad = lane >> 4, l15 = lane & 15;
  int cobase = (wave & 1)*32;
  int prow = wave >> 1;

  f32x4 acc[2][2][4];
  #pragma unroll
  for (int cv = 0; cv < 2; ++cv)
    #pragma unroll
    for (int mt = 0; mt < 2; ++mt)
      #pragma unroll
      for (int nt = 0; nt < 4; ++nt)
        acc[cv][mt][nt] = (f32x4){0.f,0.f,0.f,0.f};

  const unsigned short* Ap[2][2];
  #pragma unroll
  for (int cv = 0; cv < 2; ++cv)
    #pragma unroll
    for (int mt = 0; mt < 2; ++mt)
      Ap[cv][mt] = Asw + ((size_t)((cv*4 + (wave&1)*2 + mt)*18)*64 + lane)*8;

  #pragma unroll
  for (int tap = 0; tap < 9; ++tap){
    int pbase = (prow + tap/3)*TPOS + l15 + (tap%3);
    int pk = pbase & 7;
    #pragma unroll
    for (int cc = 0; cc < 2; ++cc){
      int kc = tap*2 + cc;
      int sl = ((quad + 4*cc) ^ pk) << 3;
      bf16x8 a[2][2], bb[4];
      #pragma unroll
      for (int cv = 0; cv < 2; ++cv)
        #pragma unroll
        for (int mt = 0; mt < 2; ++mt)
          a[cv][mt] = *(const bf16x8*)(Ap[cv][mt] + (size_t)kc*512);
      #pragma unroll
      for (int nt = 0; nt < 4; ++nt)
        bb[nt] = *(const bf16x8*)&tile[(pbase + nt*16)*64 + sl];
      #pragma unroll
      for (int cv = 0; cv < 2; ++cv)
        #pragma unroll
        for (int mt = 0; mt < 2; ++mt)
          #pragma unroll
          for (int nt = 0; nt < 4; ++nt)
            acc[cv][mt][nt] = __builtin_amdgcn_mfma_f32_16x16x32_bf16(
                a[cv][mt], bb[nt], acc[cv][mt][nt], 0, 0, 0);
    }
  }

  int gy = r0 + prow;
  #pragma unroll
  for (int mt = 0; mt < 2; ++mt){
    int co4 = cobase + mt*16 + quad*4;
    f32x4 bias0 = *(const f32x4*)&b0[co4];
    f32x4 bias1 = *(const f32x4*)&b1[co4];
    #pragma unroll
    for (int nt = 0; nt < 4; ++nt){
      int gx = c0 + nt*16 + l15;
      size_t gpix = (size_t)gy*W_ + gx;
      f32x4 v0 = acc[0][mt][nt] + bias0;
      ushort4 q;
      q.x = f2b(fmaxf(v0.x,0.f)); q.y = f2b(fmaxf(v0.y,0.f));
      q.z = f2b(fmaxf(v0.z,0.f)); q.w = f2b(fmaxf(v0.w,0.f));
      size_t toff = ((size_t)b*HW_ + gpix)*64 + co4;
      *(ushort4*)&y0t[toff] = q;
      *(ushort4*)&u[toff]   = q;
      f32x4 v1 = acc[1][mt][nt] + bias1;
      float* yo = y1out + ((size_t)b*64 + co4)*HW_ + gpix;
      yo[(size_t)0*HW_] = v1.x; yo[(size_t)1*HW_] = v1.y;
      yo[(size_t)2*HW_] = v1.z; yo[(size_t)3*HW_] = v1.w;
    }
  }
}

// ---------------- conv2 + add(out-resident y1) + relu, implicit-GEMM MFMA ----------------
__global__ __launch_bounds__(256,4) void conv2_mfma(
    const unsigned short* __restrict__ ut,    // (B,HW,64) bf16
    const unsigned short* __restrict__ Asw,
    const float* __restrict__ bias,
    float* __restrict__ out)
{
  __shared__ unsigned short tile[4*TPOS*64];
  int tid = threadIdx.x;
  int c0 = blockIdx.x*64, r0 = blockIdx.y*2, b = blockIdx.z;

  for (int e = tid; e < 4*TPOS*8; e += 256){
    int pos = e >> 3, ch = e & 7;
    int row = pos / TPOS, col = pos - row*TPOS;
    int gy = r0 - 1 + row, gx = c0 - 1 + col;
    uint4 v = {0u,0u,0u,0u};
    if (gy >= 0 && gy < H_ && gx >= 0 && gx < W_)
      v = *(const uint4*)&ut[((size_t)b*HW_ + (size_t)gy*W_ + gx)*64 + ch*8];
    *(uint4*)&tile[pos*64 + ((ch ^ (pos & 7)) << 3)] = v;
  }
  __syncthreads();

  int wave = tid >> 6, lane = tid & 63;
  int quad = lane >> 4, l15 = lane & 15;
  int cobase = (wave & 1)*32;
  int prow = wave >> 1;

  f32x4 acc[2][4];
  #pragma unroll
  for (int mt = 0; mt < 2; ++mt)
    #pragma unroll
    for (int nt = 0; nt < 4; ++nt)
      acc[mt][nt] = (f32x4){0.f,0.f,0.f,0.f};

  const unsigned short* Ap[2];
  #pragma unroll
  for (int mt = 0; mt < 2; ++mt)
    Ap[mt] = Asw + ((size_t)(((wave&1)*2 + mt)*18)*64 + lane)*8;

  #pragma unroll
  for (int tap = 0; tap < 9; ++tap){
    int pbase = (prow + tap/3)*TPOS + l15 + (tap%3);
    int pk = pbase & 7;
    #pragma unroll
    for (int cc = 0; cc < 2; ++cc){
      int kc = tap*2 + cc;
      int sl = ((quad + 4*cc) ^ pk) << 3;
      bf16x8 a[2], bb[4];
      #pragma unroll
      for (int mt = 0; mt < 2; ++mt)
        a[mt] = *(const bf16x8*)(Ap[mt] + (size_t)kc*512);
      #pragma unroll
      for (int nt = 0; nt < 4; ++nt)
        bb[nt] = *(const bf16x8*)&tile[(pbase + nt*16)*64 + sl];
      #pragma unroll
      for (int mt = 0; mt < 2; ++mt)
        #pragma unroll
        for (int nt = 0; nt < 4; ++nt)
          acc[mt][nt] = __builtin_amdgcn_mfma_f32_16x16x32_bf16(
              a[mt], bb[nt], acc[mt][nt], 0, 0, 0);
    }
  }

  int gy = r0 + prow;
  #pragma unroll
  for (int mt = 0; mt < 2; ++mt){
    int co4 = cobase + mt*16 + quad*4;
    f32x4 bs = *(const f32x4*)&bias[co4];
    #pragma unroll
    for (int nt = 0; nt < 4; ++nt){
      int gx = c0 + nt*16 + l15;
      size_t gpix = (size_t)gy*W_ + gx;
      float* yo = out + ((size_t)b*64 + co4)*HW_ + gpix;
      f32x4 v = acc[mt][nt] + bs;
      float r0v = v.x + yo[(size_t)0*HW_];
      float r1v = v.y + yo[(size_t)1*HW_];
      float r2v = v.z + yo[(size_t)2*HW_];
      float r3v = v.w + yo[(size_t)3*HW_];
      yo[(size_t)0*HW_] = r0v > 0.f ? r0v : 0.f;
      yo[(size_t)1*HW_] = r1v > 0.f ? r1v : 0.f;
      yo[(size_t)2*HW_] = r2v > 0.f ? r2v : 0.f;
      yo[(size_t)3*HW_] = r3v > 0.f ? r3v : 0.f;
    }
  }
}

// ---------------- attention: wave-per-point, zero block barriers ----------------
// One wave handles one point end-to-end. 4 waves/block. Cross-lane comms via shfl;
// per-wave LDS only for the MFMA A operand and the weighted-sum feature table.
// Per-wave LDS ops are in-order, so no __syncthreads is needed anywhere.
#define FBSTR 176   // featsB row stride in bf16 (160 data + 16 pad)
#define AW 4        // waves (=points) per block

struct __align__(16) WaveShm {
  unsigned short featsB[16][FBSTR];  // 5632 B: bf16 MFMA A operand, zero-padded
  float feats[9][64];                // 2304 B: raw gathered dnn (fp32)
  float ds[64], rs[64];              // 512 B
  float attnw[2][12];                // 96 B (softmax weights, padded)
};

__global__ __launch_bounds__(256) void attn_kernel(
    const unsigned short* __restrict__ d0t, const unsigned short* __restrict__ r0t,
    const int* __restrict__ pc_idx, const int* __restrict__ nbrs_idx,
    const float* __restrict__ disp,
    const unsigned short* __restrict__ Bmlp,
    const float* __restrict__ db2v, const float* __restrict__ dw2,
    const float* __restrict__ rb2v, const float* __restrict__ rw2,
    const float* __restrict__ dbias, const float* __restrict__ rbias,
    unsigned short* __restrict__ u_d, unsigned short* __restrict__ u_r)
{
  __shared__ WaveShm shm[AW];
  int tid = threadIdx.x;
  int wave = tid >> 6, lane = tid & 63;
  int quad = lane >> 4, l15 = lane & 15;
  int n = blockIdx.x * AW + wave;
  int b = blockIdx.y;
  WaveShm& S = shm[wave];

  int s = pc_idx[(size_t)b*Ns_ + n];
  s = __builtin_amdgcn_readfirstlane(s);

  int myidx = (lane < 9) ? nbrs_idx[((size_t)b*Ns_ + n)*K_ + lane] : 0;
  int idx8 = __shfl(myidx, 8);

  // zero featsB (pad rows/cols must be clean for MFMA)
  {
    uint4 z = {0u,0u,0u,0u};
    unsigned short* fb = &S.featsB[0][0];
    #pragma unroll
    for (int it = 0; it < 6; ++it){
      int e = it*64 + lane;
      if (e < 16*FBSTR/8) *(uint4*)&fb[e*8] = z;
    }
  }
  // disp -> featsB[k][128+m]
  if (lane < 27){
    int m = lane / 9, k = lane - m*9;
    S.featsB[k][128 + m] = f2b(disp[(((size_t)b*3 + m)*Ns_ + n)*K_ + k]);
  }

  // gather: rows 0..7 = dnn k=0..7 (8 lanes/row, uint4 = 8 bf16)
  int grow = lane >> 3, gp = lane & 7;
  int gidx = __shfl(myidx, grow);
  uint4 g1 = *(const uint4*)&d0t[((size_t)b*HW_ + (size_t)gidx)*64 + gp*8];
  // rows 8..10: dnn k=8, ds(s from d0t), rs(s from r0t)
  uint4 g2 = {0u,0u,0u,0u};
  if (lane < 24){
    int r2 = 8 + grow;
    int idx2 = (r2 == 8) ? idx8 : s;
    const unsigned short* base = (r2 == 10) ? r0t : d0t;
    g2 = *(const uint4*)&base[((size_t)b*HW_ + (size_t)idx2)*64 + gp*8];
  }

  // feats rows 0..7 (register copy kept) ; ds/rs to LDS
  float dn[8];
  {
    const unsigned short* us = (const unsigned short*)&g1;
    #pragma unroll
    for (int j = 0; j < 8; ++j){ dn[j] = b2f(us[j]); S.feats[grow][gp*8 + j] = dn[j]; }
  }
  if (lane >= 8 && lane < 24){
    const unsigned short* us = (const unsigned short*)&g2;
    float* dst = (lane < 16) ? &S.ds[(lane - 8)*8] : &S.rs[(lane - 16)*8];
    #pragma unroll
    for (int j = 0; j < 8; ++j) dst[j] = b2f(us[j]);
  }

  // featsB rows 0..7: [dnn-ds | dnn-rs]
  {
    unsigned short od[8], orr[8];
    #pragma unroll
    for (int j = 0; j < 8; ++j){
      int c = gp*8 + j;
      od[j]  = f2b(dn[j] - S.ds[c]);
      orr[j] = f2b(dn[j] - S.rs[c]);
    }
    *(uint4*)&S.featsB[grow][gp*8]      = *(uint4*)od;
    *(uint4*)&S.featsB[grow][64 + gp*8] = *(uint4*)orr;
  }
  // row 8 (lanes 0..7 hold it in g2)
  if (lane < 8){
    const unsigned short* us = (const unsigned short*)&g2;
    unsigned short od[8], orr[8];
    #pragma unroll
    for (int j = 0; j < 8; ++j){
      int c = lane*8 + j;
      float v = b2f(us[j]);
      S.feats[8][c] = v;
      od[j]  = f2b(v - S.ds[c]);
      orr[j] = f2b(v - S.rs[c]);
    }
    *(uint4*)&S.featsB[8][lane*8]      = *(uint4*)od;
    *(uint4*)&S.featsB[8][64 + lane*8] = *(uint4*)orr;
  }

  // MLP layer-1 via MFMA: this wave does all 9 n-tiles; layer-2 partials in registers
  bf16x8 afr[5];
  #pragma unroll
  for (int ks = 0; ks < 5; ++ks)
    afr[ks] = *(const bf16x8*)&S.featsB[l15][ks*32 + quad*8];

  float pd[2][4];
  #pragma unroll
  for (int m = 0; m < 2; ++m)
    #pragma unroll
    for (int r = 0; r < 4; ++r) pd[m][r] = 0.f;

  #pragma unroll
  for (int nt = 0; nt < 9; ++nt){
    f32x4 acc = (f32x4){0.f,0.f,0.f,0.f};
    const unsigned short* bp = Bmlp + ((size_t)nt*5*64 + lane)*8;
    #pragma unroll
    for (int ks = 0; ks < 5; ++ks){
      bf16x8 bfr = *(const bf16x8*)(bp + (size_t)ks*512);
      acc = __builtin_amdgcn_mfma_f32_16x16x32_bf16(afr[ks], bfr, acc, 0, 0, 0);
    }
    int jq = nt*16 + l15;
    if (jq < 2*Dh_){
      int mlp = (jq >= Dh_) ? 1 : 0;
      int j = jq - mlp*Dh_;
      float w2 = mlp ? rw2[j] : dw2[j];
      #pragma unroll
      for (int r = 0; r < 4; ++r){
        float h = acc[r];
        h = h > 0.f ? h : 0.2f*h;     // leaky relu 0.2 (pad rows give h=0)
        pd[mlp][r] += h * w2;
      }
    }
  }

  // reduce over l15 (j dimension): xor masks 1,2,4,8
  #pragma unroll
  for (int mask = 1; mask <= 8; mask <<= 1)
    #pragma unroll
    for (int m = 0; m < 2; ++m)
      #pragma unroll
      for (int r = 0; r < 4; ++r)
        pd[m][r] += __shfl_xor(pd[m][r], mask);

  // softmax over k = quad*4 + r (valid k<9), reduced across quads via masks 16,32
  float b2c[2] = { db2v[0], rb2v[0] };
  #pragma unroll
  for (int m = 0; m < 2; ++m){
    float lg[4];
    float mx = -3.4e38f;
    #pragma unroll
    for (int r = 0; r < 4; ++r){
      lg[r] = pd[m][r] + b2c[m];
      if (quad*4 + r < 9) mx = fmaxf(mx, lg[r]);
    }
    mx = fmaxf(mx, __shfl_xor(mx, 16));
    mx = fmaxf(mx, __shfl_xor(mx, 32));
    float ex[4], sum = 0.f;
    #pragma unroll
    for (int r = 0; r < 4; ++r){
      int k = quad*4 + r;
      ex[r] = (k < 9) ? __expf(lg[r] - mx) : 0.f;
      sum += ex[r];
    }
    sum += __shfl_xor(sum, 16);
    sum += __shfl_xor(sum, 32);
    float inv = 1.f / sum;
    if (l15 == 0){
      #pragma unroll
      for (int r = 0; r < 4; ++r){
        int k = quad*4 + r;
        if (k < 9) S.attnw[m][k] = ex[r] * inv;
      }
    }
  }

  // weighted sum of raw dnn + scatter (channel 0 replaces, others add residual)
  {
    int c = lane;
    #pragma unroll
    for (int m = 0; m < 2; ++m){
      float f = (m ? rbias : dbias)[c];
      #pragma unroll
      for (int k = 0; k < 9; ++k)
        f += S.attnw[m][k] * S.feats[k][c];
      float base = (c == 0) ? 0.f : (m ? S.rs[c] : S.ds[c]);
      unsigned short* u = m ? u_r : u_d;
      u[((size_t)b*HW_ + (size_t)s)*64 + c] = f2b(base + f);
    }
  }
}

// ---------------- launch ----------------
extern "C" void kernel_launch(void* const* d_in, const int* in_sizes, int n_in,
                              void* d_out, int out_size, void* d_ws, size_t ws_size,
                              hipStream_t stream)
{
  (void)in_sizes; (void)n_in; (void)out_size; (void)ws_size;

  const float* rgb       = (const float*)d_in[0];
  const float* sdepth    = (const float*)d_in[1];
  const int*   pc_idx    = (const int*)d_in[2];
  const int*   nbrs_idx  = (const int*)d_in[3];
  const float* nbrs_disp = (const float*)d_in[4];

  WPtrs wp;
  wp.w[0] = (const float*)d_in[5];   // d_conv0_w
  wp.w[1] = (const float*)d_in[7];   // d_conv1_w
  wp.w[2] = (const float*)d_in[9];   // d_conv2_w
  wp.w[3] = (const float*)d_in[11];  // r_conv0_w
  wp.w[4] = (const float*)d_in[13];  // r_conv1_w
  wp.w[5] = (const float*)d_in[15];  // r_conv2_w
  const float* d_conv0_b = (const float*)d_in[6];
  const float* d_conv1_b = (const float*)d_in[8];
  const float* d_conv2_b = (const float*)d_in[10];
  const float* r_conv0_b = (const float*)d_in[12];
  const float* r_conv1_b = (const float*)d_in[14];
  const float* r_conv2_b = (const float*)d_in[16];
  const float* d_w1 = (const float*)d_in[17];
  const float* d_w2 = (const float*)d_in[19];
  const float* d_b2 = (const float*)d_in[20];
  const float* r_w1 = (const float*)d_in[21];
  const float* r_w2 = (const float*)d_in[23];
  const float* r_b2 = (const float*)d_in[24];
  const float* d_bias = (const float*)d_in[25];
  const float* r_bias = (const float*)d_in[26];

  char* ws = (char*)d_ws;
  const size_t TSZ = (size_t)B_ * HW_ * 64 * 2;   // one transposed bf16 tensor
  unsigned short* u_d = (unsigned short*)(ws + 0*TSZ);
  unsigned short* u_r = (unsigned short*)(ws + 1*TSZ);
  unsigned short* d0t = (unsigned short*)(ws + 2*TSZ);
  unsigned short* r0t = (unsigned short*)(ws + 3*TSZ);
  unsigned short* xt  = (unsigned short*)(ws + 4*TSZ);   // transposed input (reused d then r)
  unsigned short* Asw = (unsigned short*)(ws + 5*TSZ);
  const size_t CONV_STRIDE = 4*18*64*8;           // 36864 elems per conv
  unsigned short* Bmlp = Asw + 6*CONV_STRIDE;     // 45*64*8 = 23040 elems after convs

  prep_w<<<432, 64, 0, stream>>>(wp, Asw);
  prep_wmlp<<<45, 64, 0, stream>>>(d_w1, r_w1, Bmlp);

  float* out = (float*)d_out;
  const size_t OUTSZ = (size_t)B_ * 64 * HW_;

  dim3 cgrid(W_/64, H_/2, B_);
  dim3 tgrid(HW_/128, B_);

  transpose_in<<<tgrid, 256, 0, stream>>>(sdepth, xt);
  conv01_mfma<<<cgrid, 256, 0, stream>>>(xt, Asw + 0*CONV_STRIDE,
      d_conv0_b, d_conv1_b, d0t, u_d, out);
  transpose_in<<<tgrid, 256, 0, stream>>>(rgb, xt);
  conv01_mfma<<<cgrid, 256, 0, stream>>>(xt, Asw + 3*CONV_STRIDE,
      r_conv0_b, r_conv1_b, r0t, u_r, out + OUTSZ);

  attn_kernel<<<dim3(Ns_/AW, B_), 256, 0, stream>>>(
      d0t, r0t, pc_idx, nbrs_idx, nbrs_disp,
      Bmlp,
      d_b2, d_w2, r_b2, r_w2,
      d_bias, r_bias,
      u_d, u_r);

  conv2_mfma<<<cgrid, 256, 0, stream>>>(u_d, Asw + 2*CONV_STRIDE, d_conv2_b, out);
  conv2_mfma<<<cgrid, 256, 0, stream>>>(u_r, Asw + 5*CONV_STRIDE, r_conv2_b, out + OUTSZ);
}

// Round 4
// 1260.322 us; speedup vs baseline: 1.4179x; 1.0822x over previous
//
#include <hip/hip_runtime.h>

#define H_ 256
#define W_ 1216
#define HW_ (H_*W_)
#define B_ 2
#define Ns_ 20000
#define K_ 9
#define D_ 131
#define Dh_ 65

#define TPOS 66      // positions per tile row (64 + 2 halo)
#define CSTR (4*18*64*8)   // swizzled elems per conv

typedef __attribute__((ext_vector_type(8))) short bf16x8;
typedef __attribute__((ext_vector_type(4))) float f32x4;

__device__ __forceinline__ float b2f(unsigned short u){
  union { unsigned int i; float f; } v; v.i = ((unsigned int)u) << 16; return v.f;
}
__device__ __forceinline__ unsigned short f2b(float f){
  union { float f; unsigned int i; } v; v.f = f;
  unsigned int r = (v.i + 0x7FFFu + ((v.i >> 16) & 1u)) >> 16;
  return (unsigned short)r;
}
__device__ __forceinline__ unsigned short f2h(float f){
  union { _Float16 h; unsigned short u; } v; v.h = (_Float16)f; return v.u;
}
__device__ __forceinline__ float h2f(unsigned short u){
  union { _Float16 h; unsigned short u; } v; v.u = u; return (float)v.h;
}
__device__ __forceinline__ void gld_lds16(const void* g, void* l){
  __builtin_amdgcn_global_load_lds(
      (const __attribute__((address_space(1))) unsigned int*)g,
      (__attribute__((address_space(3))) unsigned int*)l, 16, 0, 0);
}

// ---------------- weight swizzle: fp32 (C,Cin,3,3) -> bf16 MFMA A-frag order ----------------
// Layout: [conv(6)][mtile(4)][kc(18)][lane(64)][j(8)]; k = kc*32 + quad*8 + j; tap=k>>6, cin=k&63
struct WPtrs { const float* w[6]; };

__global__ void prep_w(WPtrs wp, unsigned short* __restrict__ Asw){
  int blk = blockIdx.x;                 // 6*4*18 = 432
  int c = blk / 72, rem = blk % 72, mt = rem / 18, kc = rem % 18;
  int lane = threadIdx.x;               // 64
  const float* w = wp.w[c];
  int co = mt*16 + (lane & 15);
  int kb = kc*32 + (lane >> 4)*8;
  unsigned short* dst = Asw + ((size_t)blk*64 + lane)*8;
  #pragma unroll
  for (int j = 0; j < 8; ++j){
    int k = kb + j, tap = k >> 6, cin = k & 63;
    dst[j] = f2b(w[((size_t)co*64 + cin)*9 + tap]);
  }
}

// ---------------- MLP layer-1 weight swizzle: [dw1|rw1] (131x130) -> bf16 MFMA B-frag order ----
__global__ void prep_wmlp(const float* __restrict__ dw1, const float* __restrict__ rw1,
                          unsigned short* __restrict__ Bm){
  int blk = blockIdx.x;                 // 45
  int nt = blk / 5, ks = blk % 5;
  int lane = threadIdx.x;               // 64
  int col = nt*16 + (lane & 15);
  int kb  = ks*32 + (lane >> 4)*8;
  unsigned short* dst = Bm + ((size_t)blk*64 + lane)*8;
  #pragma unroll
  for (int jj = 0; jj < 8; ++jj){
    int row = kb + jj;
    float v = 0.f;
    if (row < D_ && col < 2*Dh_)
      v = (col < Dh_) ? dw1[(size_t)row*Dh_ + col] : rw1[(size_t)row*Dh_ + (col - Dh_)];
    dst[jj] = f2b(v);
  }
}

// ---------------- fused transpose + conv0(relu) + conv1, implicit-GEMM MFMA ----------------
// Reads fp32 NCHW directly (staging does the transpose). Both tensors in one dispatch (z=4).
// y0t,u: bf16 (B,HW,64). y1h: fp16 (B,HW,64).
__global__ __launch_bounds__(256,4) void conv01_mfma(
    const float* __restrict__ xd, const float* __restrict__ xr,
    const unsigned short* __restrict__ Asw,
    const float* __restrict__ b0d, const float* __restrict__ b1d,
    const float* __restrict__ b0r, const float* __restrict__ b1r,
    unsigned short* __restrict__ d0t, unsigned short* __restrict__ u_d,
    unsigned short* __restrict__ r0t, unsigned short* __restrict__ u_r,
    unsigned short* __restrict__ y1h_d, unsigned short* __restrict__ y1h_r)
{
  __shared__ unsigned short tile[4*TPOS*64];
  int tid = threadIdx.x;
  int c0 = blockIdx.x*64, r0 = blockIdx.y*2;
  int t = blockIdx.z >> 1, b = blockIdx.z & 1;

  const float* x = t ? xr : xd;
  const unsigned short* Aswt = Asw + (size_t)(t ? 3 : 0)*CSTR;

  // stage 4 rows x 66 cols x 64 cin: fp32 NCHW -> bf16 LDS, slot-XOR swizzled.
  // lane pattern: 8 pos x 8 slots per instruction; pos advances 32/iter so the
  // 128B lines fetched (32B used each) are fully consumed within the block.
  for (int e = tid; e < 4*TPOS*8; e += 256){
    int pos = e >> 3, slot = e & 7;
    int row = pos / TPOS, col = pos - row*TPOS;
    int gy = r0 - 1 + row, gx = c0 - 1 + col;
    int c8 = slot ^ (pos & 7);          // data for channel-group c8 lives at this slot
    union { unsigned short us[8]; uint4 v; } pk;
    if (gy >= 0 && gy < H_ && gx >= 0 && gx < W_){
      const float* sp = x + ((size_t)b*64 + c8*8)*HW_ + (size_t)gy*W_ + gx;
      #pragma unroll
      for (int j = 0; j < 8; ++j) pk.us[j] = f2b(sp[(size_t)j*HW_]);
    } else {
      pk.v = (uint4){0u,0u,0u,0u};
    }
    *(uint4*)&tile[pos*64 + slot*8] = pk.v;
  }
  __syncthreads();

  int wave = tid >> 6, lane = tid & 63;
  int quad = lane >> 4, l15 = lane & 15;
  int cobase = (wave & 1)*32;
  int prow = wave >> 1;

  f32x4 acc[2][2][4];
  #pragma unroll
  for (int cv = 0; cv < 2; ++cv)
    #pragma unroll
    for (int mt = 0; mt < 2; ++mt)
      #pragma unroll
      for (int nt = 0; nt < 4; ++nt)
        acc[cv][mt][nt] = (f32x4){0.f,0.f,0.f,0.f};

  const unsigned short* Ap[2][2];
  #pragma unroll
  for (int cv = 0; cv < 2; ++cv)
    #pragma unroll
    for (int mt = 0; mt < 2; ++mt)
      Ap[cv][mt] = Aswt + ((size_t)((cv*4 + (wave&1)*2 + mt)*18)*64 + lane)*8;

  #pragma unroll
  for (int tap = 0; tap < 9; ++tap){
    int pbase = (prow + tap/3)*TPOS + l15 + (tap%3);
    int pk = pbase & 7;
    #pragma unroll
    for (int cc = 0; cc < 2; ++cc){
      int kc = tap*2 + cc;
      int sl = ((quad + 4*cc) ^ pk) << 3;
      bf16x8 a[2][2], bb[4];
      #pragma unroll
      for (int cv = 0; cv < 2; ++cv)
        #pragma unroll
        for (int mt = 0; mt < 2; ++mt)
          a[cv][mt] = *(const bf16x8*)(Ap[cv][mt] + (size_t)kc*512);
      #pragma unroll
      for (int nt = 0; nt < 4; ++nt)
        bb[nt] = *(const bf16x8*)&tile[(pbase + nt*16)*64 + sl];
      #pragma unroll
      for (int cv = 0; cv < 2; ++cv)
        #pragma unroll
        for (int mt = 0; mt < 2; ++mt)
          #pragma unroll
          for (int nt = 0; nt < 4; ++nt)
            acc[cv][mt][nt] = __builtin_amdgcn_mfma_f32_16x16x32_bf16(
                a[cv][mt], bb[nt], acc[cv][mt][nt], 0, 0, 0);
    }
  }

  unsigned short* y0t = t ? r0t : d0t;
  unsigned short* u   = t ? u_r  : u_d;
  unsigned short* y1h = t ? y1h_r : y1h_d;
  const float* b0 = t ? b0r : b0d;
  const float* b1 = t ? b1r : b1d;

  int gy = r0 + prow;
  #pragma unroll
  for (int mt = 0; mt < 2; ++mt){
    int co4 = cobase + mt*16 + quad*4;
    f32x4 bias0 = *(const f32x4*)&b0[co4];
    f32x4 bias1 = *(const f32x4*)&b1[co4];
    #pragma unroll
    for (int nt = 0; nt < 4; ++nt){
      int gx = c0 + nt*16 + l15;
      size_t gpix = (size_t)gy*W_ + gx;
      size_t toff = ((size_t)b*HW_ + gpix)*64 + co4;
      f32x4 v0 = acc[0][mt][nt] + bias0;
      ushort4 q;
      q.x = f2b(fmaxf(v0.x,0.f)); q.y = f2b(fmaxf(v0.y,0.f));
      q.z = f2b(fmaxf(v0.z,0.f)); q.w = f2b(fmaxf(v0.w,0.f));
      *(ushort4*)&y0t[toff] = q;
      *(ushort4*)&u[toff]   = q;
      f32x4 v1 = acc[1][mt][nt] + bias1;
      ushort4 h;
      h.x = f2h(v1.x); h.y = f2h(v1.y); h.z = f2h(v1.z); h.w = f2h(v1.w);
      *(ushort4*)&y1h[toff] = h;
    }
  }
}

// ---------------- conv2 + add(y1h) + relu -> fp32 NCHW out ----------------
// Staging via global_load_lds (pre-swizzled per-lane source, linear LDS dest).
__global__ __launch_bounds__(256,4) void conv2_mfma(
    const unsigned short* __restrict__ u_d, const unsigned short* __restrict__ u_r,
    const unsigned short* __restrict__ Asw,
    const float* __restrict__ biasd, const float* __restrict__ biasr,
    const unsigned short* __restrict__ y1h_d, const unsigned short* __restrict__ y1h_r,
    float* __restrict__ out)
{
  __shared__ unsigned short tile[4*TPOS*64];
  int tid = threadIdx.x;
  int c0 = blockIdx.x*64, r0 = blockIdx.y*2;
  int t = blockIdx.z >> 1, b = blockIdx.z & 1;

  const unsigned short* ut  = t ? u_r : u_d;
  const unsigned short* y1h = t ? y1h_r : y1h_d;
  const unsigned short* Aswt = Asw + (size_t)(t ? 5 : 2)*CSTR;
  const float* bias = t ? biasr : biasd;
  float* o = out + (size_t)t * B_ * 64 * HW_;

  {
    int wave = tid >> 6, lane = tid & 63;
    // wave handles uint4-elements [wave*528, wave*528+528): 8 full iters + 16-lane tail
    #pragma unroll 1
    for (int it = 0; it < 9; ++it){
      int e = wave*528 + it*64 + lane;
      bool active = (it < 8) || (lane < 16);
      if (active){
        int pos = e >> 3, slot = e & 7;
        int row = pos / TPOS, col = pos - row*TPOS;
        int gy = r0 - 1 + row, gx = c0 - 1 + col;
        int c8 = slot ^ (pos & 7);      // pre-swizzled source so linear dest = swizzled layout
        if (gy >= 0 && gy < H_ && gx >= 0 && gx < W_){
          const unsigned short* src = &ut[((size_t)b*HW_ + (size_t)gy*W_ + gx)*64 + c8*8];
          gld_lds16(src, &tile[(size_t)(wave*528 + it*64)*8]);
        } else {
          *(uint4*)&tile[(size_t)e*8] = (uint4){0u,0u,0u,0u};
        }
      }
    }
  }
  __syncthreads();

  int wave = tid >> 6, lane = tid & 63;
  int quad = lane >> 4, l15 = lane & 15;
  int cobase = (wave & 1)*32;
  int prow = wave >> 1;

  f32x4 acc[2][4];
  #pragma unroll
  for (int mt = 0; mt < 2; ++mt)
    #pragma unroll
    for (int nt = 0; nt < 4; ++nt)
      acc[mt][nt] = (f32x4){0.f,0.f,0.f,0.f};

  const unsigned short* Ap[2];
  #pragma unroll
  for (int mt = 0; mt < 2; ++mt)
    Ap[mt] = Aswt + ((size_t)(((wave&1)*2 + mt)*18)*64 + lane)*8;

  #pragma unroll
  for (int tap = 0; tap < 9; ++tap){
    int pbase = (prow + tap/3)*TPOS + l15 + (tap%3);
    int pk = pbase & 7;
    #pragma unroll
    for (int cc = 0; cc < 2; ++cc){
      int kc = tap*2 + cc;
      int sl = ((quad + 4*cc) ^ pk) << 3;
      bf16x8 a[2], bb[4];
      #pragma unroll
      for (int mt = 0; mt < 2; ++mt)
        a[mt] = *(const bf16x8*)(Ap[mt] + (size_t)kc*512);
      #pragma unroll
      for (int nt = 0; nt < 4; ++nt)
        bb[nt] = *(const bf16x8*)&tile[(pbase + nt*16)*64 + sl];
      #pragma unroll
      for (int mt = 0; mt < 2; ++mt)
        #pragma unroll
        for (int nt = 0; nt < 4; ++nt)
          acc[mt][nt] = __builtin_amdgcn_mfma_f32_16x16x32_bf16(
              a[mt], bb[nt], acc[mt][nt], 0, 0, 0);
    }
  }

  int gy = r0 + prow;
  #pragma unroll
  for (int mt = 0; mt < 2; ++mt){
    int co4 = cobase + mt*16 + quad*4;
    f32x4 bs = *(const f32x4*)&bias[co4];
    #pragma unroll
    for (int nt = 0; nt < 4; ++nt){
      int gx = c0 + nt*16 + l15;
      size_t gpix = (size_t)gy*W_ + gx;
      ushort4 h = *(const ushort4*)&y1h[((size_t)b*HW_ + gpix)*64 + co4];
      f32x4 v = acc[mt][nt] + bs;
      float r0v = v.x + h2f(h.x);
      float r1v = v.y + h2f(h.y);
      float r2v = v.z + h2f(h.z);
      float r3v = v.w + h2f(h.w);
      float* yo = o + ((size_t)b*64 + co4)*HW_ + gpix;
      yo[(size_t)0*HW_] = r0v > 0.f ? r0v : 0.f;
      yo[(size_t)1*HW_] = r1v > 0.f ? r1v : 0.f;
      yo[(size_t)2*HW_] = r2v > 0.f ? r2v : 0.f;
      yo[(size_t)3*HW_] = r3v > 0.f ? r3v : 0.f;
    }
  }
}

// ---------------- attention: wave-per-point, zero block barriers ----------------
#define FBSTR 176   // featsB row stride in bf16 (160 data + 16 pad)
#define AW 4        // waves (=points) per block

struct __align__(16) WaveShm {
  unsigned short featsB[16][FBSTR];  // 5632 B: bf16 MFMA A operand, zero-padded
  float feats[9][64];                // 2304 B: raw gathered dnn (fp32)
  float ds[64], rs[64];              // 512 B
  float attnw[2][12];                // 96 B (softmax weights, padded)
};

__global__ __launch_bounds__(256) void attn_kernel(
    const unsigned short* __restrict__ d0t, const unsigned short* __restrict__ r0t,
    const int* __restrict__ pc_idx, const int* __restrict__ nbrs_idx,
    const float* __restrict__ disp,
    const unsigned short* __restrict__ Bmlp,
    const float* __restrict__ db2v, const float* __restrict__ dw2,
    const float* __restrict__ rb2v, const float* __restrict__ rw2,
    const float* __restrict__ dbias, const float* __restrict__ rbias,
    unsigned short* __restrict__ u_d, unsigned short* __restrict__ u_r)
{
  __shared__ WaveShm shm[AW];
  int tid = threadIdx.x;
  int wave = tid >> 6, lane = tid & 63;
  int quad = lane >> 4, l15 = lane & 15;
  int n = blockIdx.x * AW + wave;
  int b = blockIdx.y;
  WaveShm& S = shm[wave];

  int s = pc_idx[(size_t)b*Ns_ + n];
  s = __builtin_amdgcn_readfirstlane(s);

  int myidx = (lane < 9) ? nbrs_idx[((size_t)b*Ns_ + n)*K_ + lane] : 0;
  int idx8 = __shfl(myidx, 8);

  // zero featsB (pad rows/cols must be clean for MFMA)
  {
    uint4 z = {0u,0u,0u,0u};
    unsigned short* fb = &S.featsB[0][0];
    #pragma unroll
    for (int it = 0; it < 6; ++it){
      int e = it*64 + lane;
      if (e < 16*FBSTR/8) *(uint4*)&fb[e*8] = z;
    }
  }
  // disp -> featsB[k][128+m]
  if (lane < 27){
    int m = lane / 9, k = lane - m*9;
    S.featsB[k][128 + m] = f2b(disp[(((size_t)b*3 + m)*Ns_ + n)*K_ + k]);
  }

  // gather: rows 0..7 = dnn k=0..7 (8 lanes/row, uint4 = 8 bf16)
  int grow = lane >> 3, gp = lane & 7;
  int gidx = __shfl(myidx, grow);
  uint4 g1 = *(const uint4*)&d0t[((size_t)b*HW_ + (size_t)gidx)*64 + gp*8];
  // rows 8..10: dnn k=8, ds(s from d0t), rs(s from r0t)
  uint4 g2 = {0u,0u,0u,0u};
  if (lane < 24){
    int r2 = 8 + grow;
    int idx2 = (r2 == 8) ? idx8 : s;
    const unsigned short* base = (r2 == 10) ? r0t : d0t;
    g2 = *(const uint4*)&base[((size_t)b*HW_ + (size_t)idx2)*64 + gp*8];
  }

  // feats rows 0..7 (register copy kept) ; ds/rs to LDS
  float dn[8];
  {
    const unsigned short* us = (const unsigned short*)&g1;
    #pragma unroll
    for (int j = 0; j < 8; ++j){ dn[j] = b2f(us[j]); S.feats[grow][gp*8 + j] = dn[j]; }
  }
  if (lane >= 8 && lane < 24){
    const unsigned short* us = (const unsigned short*)&g2;
    float* dst = (lane < 16) ? &S.ds[(lane - 8)*8] : &S.rs[(lane - 16)*8];
    #pragma unroll
    for (int j = 0; j < 8; ++j) dst[j] = b2f(us[j]);
  }

  // featsB rows 0..7: [dnn-ds | dnn-rs]
  {
    unsigned short od[8], orr[8];
    #pragma unroll
    for (int j = 0; j < 8; ++j){
      int c = gp*8 + j;
      od[j]  = f2b(dn[j] - S.ds[c]);
      orr[j] = f2b(dn[j] - S.rs[c]);
    }
    *(uint4*)&S.featsB[grow][gp*8]      = *(uint4*)od;
    *(uint4*)&S.featsB[grow][64 + gp*8] = *(uint4*)orr;
  }
  // row 8 (lanes 0..7 hold it in g2)
  if (lane < 8){
    const unsigned short* us = (const unsigned short*)&g2;
    unsigned short od[8], orr[8];
    #pragma unroll
    for (int j = 0; j < 8; ++j){
      int c = lane*8 + j;
      float v = b2f(us[j]);
      S.feats[8][c] = v;
      od[j]  = f2b(v - S.ds[c]);
      orr[j] = f2b(v - S.rs[c]);
    }
    *(uint4*)&S.featsB[8][lane*8]      = *(uint4*)od;
    *(uint4*)&S.featsB[8][64 + lane*8] = *(uint4*)orr;
  }

  // MLP layer-1 via MFMA: this wave does all 9 n-tiles; layer-2 partials in registers
  bf16x8 afr[5];
  #pragma unroll
  for (int ks = 0; ks < 5; ++ks)
    afr[ks] = *(const bf16x8*)&S.featsB[l15][ks*32 + quad*8];

  float pd[2][4];
  #pragma unroll
  for (int m = 0; m < 2; ++m)
    #pragma unroll
    for (int r = 0; r < 4; ++r) pd[m][r] = 0.f;

  #pragma unroll
  for (int nt = 0; nt < 9; ++nt){
    f32x4 acc = (f32x4){0.f,0.f,0.f,0.f};
    const unsigned short* bp = Bmlp + ((size_t)nt*5*64 + lane)*8;
    #pragma unroll
    for (int ks = 0; ks < 5; ++ks){
      bf16x8 bfr = *(const bf16x8*)(bp + (size_t)ks*512);
      acc = __builtin_amdgcn_mfma_f32_16x16x32_bf16(afr[ks], bfr, acc, 0, 0, 0);
    }
    int jq = nt*16 + l15;
    if (jq < 2*Dh_){
      int mlp = (jq >= Dh_) ? 1 : 0;
      int j = jq - mlp*Dh_;
      float w2 = mlp ? rw2[j] : dw2[j];
      #pragma unroll
      for (int r = 0; r < 4; ++r){
        float h = acc[r];
        h = h > 0.f ? h : 0.2f*h;     // leaky relu 0.2 (pad rows give h=0)
        pd[mlp][r] += h * w2;
      }
    }
  }

  // reduce over l15 (j dimension): xor masks 1,2,4,8
  #pragma unroll
  for (int mask = 1; mask <= 8; mask <<= 1)
    #pragma unroll
    for (int m = 0; m < 2; ++m)
      #pragma unroll
      for (int r = 0; r < 4; ++r)
        pd[m][r] += __shfl_xor(pd[m][r], mask);

  // softmax over k = quad*4 + r (valid k<9), reduced across quads via masks 16,32
  float b2c[2] = { db2v[0], rb2v[0] };
  #pragma unroll
  for (int m = 0; m < 2; ++m){
    float lg[4];
    float mx = -3.4e38f;
    #pragma unroll
    for (int r = 0; r < 4; ++r){
      lg[r] = pd[m][r] + b2c[m];
      if (quad*4 + r < 9) mx = fmaxf(mx, lg[r]);
    }
    mx = fmaxf(mx, __shfl_xor(mx, 16));
    mx = fmaxf(mx, __shfl_xor(mx, 32));
    float ex[4], sum = 0.f;
    #pragma unroll
    for (int r = 0; r < 4; ++r){
      int k = quad*4 + r;
      ex[r] = (k < 9) ? __expf(lg[r] - mx) : 0.f;
      sum += ex[r];
    }
    sum += __shfl_xor(sum, 16);
    sum += __shfl_xor(sum, 32);
    float inv = 1.f / sum;
    if (l15 == 0){
      #pragma unroll
      for (int r = 0; r < 4; ++r){
        int k = quad*4 + r;
        if (k < 9) S.attnw[m][k] = ex[r] * inv;
      }
    }
  }

  // weighted sum of raw dnn + scatter (channel 0 replaces, others add residual)
  {
    int c = lane;
    #pragma unroll
    for (int m = 0; m < 2; ++m){
      float f = (m ? rbias : dbias)[c];
      #pragma unroll
      for (int k = 0; k < 9; ++k)
        f += S.attnw[m][k] * S.feats[k][c];
      float base = (c == 0) ? 0.f : (m ? S.rs[c] : S.ds[c]);
      unsigned short* u = m ? u_r : u_d;
      u[((size_t)b*HW_ + (size_t)s)*64 + c] = f2b(base + f);
    }
  }
}

// ---------------- launch ----------------
extern "C" void kernel_launch(void* const* d_in, const int* in_sizes, int n_in,
                              void* d_out, int out_size, void* d_ws, size_t ws_size,
                              hipStream_t stream)
{
  (void)in_sizes; (void)n_in; (void)out_size; (void)ws_size;

  const float* rgb       = (const float*)d_in[0];
  const float* sdepth    = (const float*)d_in[1];
  const int*   pc_idx    = (const int*)d_in[2];
  const int*   nbrs_idx  = (const int*)d_in[3];
  const float* nbrs_disp = (const float*)d_in[4];

  WPtrs wp;
  wp.w[0] = (const float*)d_in[5];   // d_conv0_w
  wp.w[1] = (const float*)d_in[7];   // d_conv1_w
  wp.w[2] = (const float*)d_in[9];   // d_conv2_w
  wp.w[3] = (const float*)d_in[11];  // r_conv0_w
  wp.w[4] = (const float*)d_in[13];  // r_conv1_w
  wp.w[5] = (const float*)d_in[15];  // r_conv2_w
  const float* d_conv0_b = (const float*)d_in[6];
  const float* d_conv1_b = (const float*)d_in[8];
  const float* d_conv2_b = (const float*)d_in[10];
  const float* r_conv0_b = (const float*)d_in[12];
  const float* r_conv1_b = (const float*)d_in[14];
  const float* r_conv2_b = (const float*)d_in[16];
  const float* d_w1 = (const float*)d_in[17];
  const float* d_w2 = (const float*)d_in[19];
  const float* d_b2 = (const float*)d_in[20];
  const float* r_w1 = (const float*)d_in[21];
  const float* r_w2 = (const float*)d_in[23];
  const float* r_b2 = (const float*)d_in[24];
  const float* d_bias = (const float*)d_in[25];
  const float* r_bias = (const float*)d_in[26];

  char* ws = (char*)d_ws;
  const size_t TSZ = (size_t)B_ * HW_ * 64 * 2;   // one (B,HW,64) 2-byte tensor
  unsigned short* u_d   = (unsigned short*)(ws + 0*TSZ);
  unsigned short* u_r   = (unsigned short*)(ws + 1*TSZ);
  unsigned short* d0t   = (unsigned short*)(ws + 2*TSZ);
  unsigned short* r0t   = (unsigned short*)(ws + 3*TSZ);
  unsigned short* y1h_d = (unsigned short*)(ws + 4*TSZ);
  unsigned short* y1h_r = (unsigned short*)(ws + 5*TSZ);
  unsigned short* Asw   = (unsigned short*)(ws + 6*TSZ);
  unsigned short* Bmlp  = Asw + 6*CSTR;           // 45*64*8 elems after convs

  prep_w<<<432, 64, 0, stream>>>(wp, Asw);
  prep_wmlp<<<45, 64, 0, stream>>>(d_w1, r_w1, Bmlp);

  float* out = (float*)d_out;

  dim3 cgrid(W_/64, H_/2, 4);   // z = tensor*2 + batch

  conv01_mfma<<<cgrid, 256, 0, stream>>>(sdepth, rgb, Asw,
      d_conv0_b, d_conv1_b, r_conv0_b, r_conv1_b,
      d0t, u_d, r0t, u_r, y1h_d, y1h_r);

  attn_kernel<<<dim3(Ns_/AW, B_), 256, 0, stream>>>(
      d0t, r0t, pc_idx, nbrs_idx, nbrs_disp,
      Bmlp,
      d_b2, d_w2, r_b2, r_w2,
      d_bias, r_bias,
      u_d, u_r);

  conv2_mfma<<<cgrid, 256, 0, stream>>>(u_d, u_r, Asw,
      d_conv2_b, r_conv2_b, y1h_d, y1h_r, out);
}

// Round 6
// 1142.243 us; speedup vs baseline: 1.5645x; 1.1034x over previous
//
#include <hip/hip_runtime.h>

#define H_ 256
#define W_ 1216
#define HW_ (H_*W_)
#define B_ 2
#define Ns_ 20000
#define K_ 9
#define D_ 131
#define Dh_ 65

#define TPOS 66            // positions per tile row (64 + 2 halo)
#define CSTR (4*18*64*8)   // swizzled elems per conv
#define ROWS 4             // output rows per block (6 staged rows -> 1.5x halo)

typedef __attribute__((ext_vector_type(8))) short bf16x8;
typedef __attribute__((ext_vector_type(4))) float f32x4;

__device__ __forceinline__ float b2f(unsigned short u){
  union { unsigned int i; float f; } v; v.i = ((unsigned int)u) << 16; return v.f;
}
__device__ __forceinline__ unsigned short f2b(float f){
  union { float f; unsigned int i; } v; v.f = f;
  unsigned int r = (v.i + 0x7FFFu + ((v.i >> 16) & 1u)) >> 16;
  return (unsigned short)r;
}
__device__ __forceinline__ unsigned short f2h(float f){
  union { _Float16 h; unsigned short u; } v; v.h = (_Float16)f; return v.u;
}
__device__ __forceinline__ float h2f(unsigned short u){
  union { _Float16 h; unsigned short u; } v; v.u = u; return (float)v.h;
}
__device__ __forceinline__ void gld_lds16(const void* g, void* l){
  __builtin_amdgcn_global_load_lds(
      (const __attribute__((address_space(1))) unsigned int*)g,
      (__attribute__((address_space(3))) unsigned int*)l, 16, 0, 0);
}

// ---------------- weight swizzle: fp32 (C,Cin,3,3) -> bf16 MFMA A-frag order ----------------
// Layout: [conv(6)][mtile(4)][kc(18)][lane(64)][j(8)]; k = kc*32 + quad*8 + j; tap=k>>6, cin=k&63
struct WPtrs { const float* w[6]; };

__global__ void prep_w(WPtrs wp, unsigned short* __restrict__ Asw){
  int blk = blockIdx.x;                 // 6*4*18 = 432
  int c = blk / 72, rem = blk % 72, mt = rem / 18, kc = rem % 18;
  int lane = threadIdx.x;               // 64
  const float* w = wp.w[c];
  int co = mt*16 + (lane & 15);
  int kb = kc*32 + (lane >> 4)*8;
  unsigned short* dst = Asw + ((size_t)blk*64 + lane)*8;
  #pragma unroll
  for (int j = 0; j < 8; ++j){
    int k = kb + j, tap = k >> 6, cin = k & 63;
    dst[j] = f2b(w[((size_t)co*64 + cin)*9 + tap]);
  }
}

// ---------------- MLP layer-1 weight swizzle: [dw1|rw1] (131x130) -> bf16 MFMA B-frag order ----
__global__ void prep_wmlp(const float* __restrict__ dw1, const float* __restrict__ rw1,
                          unsigned short* __restrict__ Bm){
  int blk = blockIdx.x;                 // 45
  int nt = blk / 5, ks = blk % 5;
  int lane = threadIdx.x;               // 64
  int col = nt*16 + (lane & 15);
  int kb  = ks*32 + (lane >> 4)*8;
  unsigned short* dst = Bm + ((size_t)blk*64 + lane)*8;
  #pragma unroll
  for (int jj = 0; jj < 8; ++jj){
    int row = kb + jj;
    float v = 0.f;
    if (row < D_ && col < 2*Dh_)
      v = (col < Dh_) ? dw1[(size_t)row*Dh_ + col] : rw1[(size_t)row*Dh_ + (col - Dh_)];
    dst[jj] = f2b(v);
  }
}

// ---------------- fused transpose + conv0(relu) + conv1, implicit-GEMM MFMA ----------------
// 512 threads, 4 output rows/block (6 staged rows). Reads fp32 NCHW directly.
// u: bf16 (B,HW,64) [single copy]. y1h: fp16 (B,HW,64).
__global__ __launch_bounds__(512,4) void conv01_mfma(
    const float* __restrict__ xd, const float* __restrict__ xr,
    const unsigned short* __restrict__ Asw,
    const float* __restrict__ b0d, const float* __restrict__ b1d,
    const float* __restrict__ b0r, const float* __restrict__ b1r,
    unsigned short* __restrict__ u_d, unsigned short* __restrict__ u_r,
    unsigned short* __restrict__ y1h_d, unsigned short* __restrict__ y1h_r)
{
  __shared__ unsigned short tile[(ROWS+2)*TPOS*64];
  int tid = threadIdx.x;
  int c0 = blockIdx.x*64, r0 = blockIdx.y*ROWS;
  int t = blockIdx.z >> 1, b = blockIdx.z & 1;

  const float* x = t ? xr : xd;
  const unsigned short* Aswt = Asw + (size_t)(t ? 3 : 0)*CSTR;

  // stage (ROWS+2) rows x 66 cols x 64 cin: fp32 NCHW -> bf16 LDS, slot-XOR swizzled
  for (int e = tid; e < (ROWS+2)*TPOS*8; e += 512){
    int pos = e >> 3, slot = e & 7;
    int row = pos / TPOS, col = pos - row*TPOS;
    int gy = r0 - 1 + row, gx = c0 - 1 + col;
    int c8 = slot ^ (pos & 7);          // data for channel-group c8 lives at this slot
    union { unsigned short us[8]; uint4 v; } pk;
    if (gy >= 0 && gy < H_ && gx >= 0 && gx < W_){
      const float* sp = x + ((size_t)b*64 + c8*8)*HW_ + (size_t)gy*W_ + gx;
      #pragma unroll
      for (int j = 0; j < 8; ++j) pk.us[j] = f2b(sp[(size_t)j*HW_]);
    } else {
      pk.v = (uint4){0u,0u,0u,0u};
    }
    *(uint4*)&tile[pos*64 + slot*8] = pk.v;
  }
  __syncthreads();

  int wave = tid >> 6, lane = tid & 63;
  int quad = lane >> 4, l15 = lane & 15;
  int cobase = (wave & 1)*32;
  int prow = wave >> 1;                 // 0..3

  f32x4 acc[2][2][4];
  #pragma unroll
  for (int cv = 0; cv < 2; ++cv)
    #pragma unroll
    for (int mt = 0; mt < 2; ++mt)
      #pragma unroll
      for (int nt = 0; nt < 4; ++nt)
        acc[cv][mt][nt] = (f32x4){0.f,0.f,0.f,0.f};

  const unsigned short* Ap[2][2];
  #pragma unroll
  for (int cv = 0; cv < 2; ++cv)
    #pragma unroll
    for (int mt = 0; mt < 2; ++mt)
      Ap[cv][mt] = Aswt + ((size_t)((cv*4 + (wave&1)*2 + mt)*18)*64 + lane)*8;

  #pragma unroll
  for (int tap = 0; tap < 9; ++tap){
    int pbase = (prow + tap/3)*TPOS + l15 + (tap%3);
    int pk = pbase & 7;
    #pragma unroll
    for (int cc = 0; cc < 2; ++cc){
      int kc = tap*2 + cc;
      int sl = ((quad + 4*cc) ^ pk) << 3;
      bf16x8 a[2][2], bb[4];
      #pragma unroll
      for (int cv = 0; cv < 2; ++cv)
        #pragma unroll
        for (int mt = 0; mt < 2; ++mt)
          a[cv][mt] = *(const bf16x8*)(Ap[cv][mt] + (size_t)kc*512);
      #pragma unroll
      for (int nt = 0; nt < 4; ++nt)
        bb[nt] = *(const bf16x8*)&tile[(pbase + nt*16)*64 + sl];
      #pragma unroll
      for (int cv = 0; cv < 2; ++cv)
        #pragma unroll
        for (int mt = 0; mt < 2; ++mt)
          #pragma unroll
          for (int nt = 0; nt < 4; ++nt)
            acc[cv][mt][nt] = __builtin_amdgcn_mfma_f32_16x16x32_bf16(
                a[cv][mt], bb[nt], acc[cv][mt][nt], 0, 0, 0);
    }
  }

  unsigned short* u   = t ? u_r   : u_d;
  unsigned short* y1h = t ? y1h_r : y1h_d;
  const float* b0 = t ? b0r : b0d;
  const float* b1 = t ? b1r : b1d;

  int gy = r0 + prow;
  #pragma unroll
  for (int mt = 0; mt < 2; ++mt){
    int co4 = cobase + mt*16 + quad*4;
    f32x4 bias0 = *(const f32x4*)&b0[co4];
    f32x4 bias1 = *(const f32x4*)&b1[co4];
    #pragma unroll
    for (int nt = 0; nt < 4; ++nt){
      int gx = c0 + nt*16 + l15;
      size_t gpix = (size_t)gy*W_ + gx;
      size_t toff = ((size_t)b*HW_ + gpix)*64 + co4;
      f32x4 v0 = acc[0][mt][nt] + bias0;
      ushort4 q;
      q.x = f2b(fmaxf(v0.x,0.f)); q.y = f2b(fmaxf(v0.y,0.f));
      q.z = f2b(fmaxf(v0.z,0.f)); q.w = f2b(fmaxf(v0.w,0.f));
      *(ushort4*)&u[toff] = q;
      f32x4 v1 = acc[1][mt][nt] + bias1;
      ushort4 h;
      h.x = f2h(v1.x); h.y = f2h(v1.y); h.z = f2h(v1.z); h.w = f2h(v1.w);
      *(ushort4*)&y1h[toff] = h;
    }
  }
}

// ---------------- conv2 + add(y1h) + relu -> fp32 NCHW out ----------------
// 512 threads, 4 output rows/block. Staging via global_load_lds (pre-swizzled source).
#define C2ELEM ((ROWS+2)*TPOS*8)      // 3168 uint4 elements
#define C2PW   (C2ELEM/8)             // 396 per wave

__global__ __launch_bounds__(512,4) void conv2_mfma(
    const unsigned short* __restrict__ u_d, const unsigned short* __restrict__ u_r,
    const unsigned short* __restrict__ Asw,
    const float* __restrict__ biasd, const float* __restrict__ biasr,
    const unsigned short* __restrict__ y1h_d, const unsigned short* __restrict__ y1h_r,
    float* __restrict__ out)
{
  __shared__ unsigned short tile[(ROWS+2)*TPOS*64];
  int tid = threadIdx.x;
  int c0 = blockIdx.x*64, r0 = blockIdx.y*ROWS;
  int t = blockIdx.z >> 1, b = blockIdx.z & 1;

  const unsigned short* ut  = t ? u_r : u_d;
  const unsigned short* y1h = t ? y1h_r : y1h_d;
  const unsigned short* Aswt = Asw + (size_t)(t ? 5 : 2)*CSTR;
  const float* bias = t ? biasr : biasd;
  float* o = out + (size_t)t * B_ * 64 * HW_;

  int wave = tid >> 6, lane = tid & 63;
  {
    #pragma unroll 1
    for (int it = 0; it < 7; ++it){
      int off = it*64 + lane;
      if (off < C2PW){
        int e = wave*C2PW + off;
        int pos = e >> 3, slot = e & 7;
        int row = pos / TPOS, col = pos - row*TPOS;
        int gy = r0 - 1 + row, gx = c0 - 1 + col;
        int c8 = slot ^ (pos & 7);      // pre-swizzled source: linear dest = swizzled layout
        if (gy >= 0 && gy < H_ && gx >= 0 && gx < W_){
          const unsigned short* src = &ut[((size_t)b*HW_ + (size_t)gy*W_ + gx)*64 + c8*8];
          gld_lds16(src, &tile[(size_t)(wave*C2PW + it*64)*8]);
        } else {
          *(uint4*)&tile[(size_t)e*8] = (uint4){0u,0u,0u,0u};
        }
      }
    }
  }
  __syncthreads();

  int quad = lane >> 4, l15 = lane & 15;
  int cobase = (wave & 1)*32;
  int prow = wave >> 1;

  f32x4 acc[2][4];
  #pragma unroll
  for (int mt = 0; mt < 2; ++mt)
    #pragma unroll
    for (int nt = 0; nt < 4; ++nt)
      acc[mt][nt] = (f32x4){0.f,0.f,0.f,0.f};

  const unsigned short* Ap[2];
  #pragma unroll
  for (int mt = 0; mt < 2; ++mt)
    Ap[mt] = Aswt + ((size_t)(((wave&1)*2 + mt)*18)*64 + lane)*8;

  #pragma unroll
  for (int tap = 0; tap < 9; ++tap){
    int pbase = (prow + tap/3)*TPOS + l15 + (tap%3);
    int pk = pbase & 7;
    #pragma unroll
    for (int cc = 0; cc < 2; ++cc){
      int kc = tap*2 + cc;
      int sl = ((quad + 4*cc) ^ pk) << 3;
      bf16x8 a[2], bb[4];
      #pragma unroll
      for (int mt = 0; mt < 2; ++mt)
        a[mt] = *(const bf16x8*)(Ap[mt] + (size_t)kc*512);
      #pragma unroll
      for (int nt = 0; nt < 4; ++nt)
        bb[nt] = *(const bf16x8*)&tile[(pbase + nt*16)*64 + sl];
      #pragma unroll
      for (int mt = 0; mt < 2; ++mt)
        #pragma unroll
        for (int nt = 0; nt < 4; ++nt)
          acc[mt][nt] = __builtin_amdgcn_mfma_f32_16x16x32_bf16(
              a[mt], bb[nt], acc[mt][nt], 0, 0, 0);
    }
  }

  int gy = r0 + prow;
  #pragma unroll
  for (int mt = 0; mt < 2; ++mt){
    int co4 = cobase + mt*16 + quad*4;
    f32x4 bs = *(const f32x4*)&bias[co4];
    #pragma unroll
    for (int nt = 0; nt < 4; ++nt){
      int gx = c0 + nt*16 + l15;
      size_t gpix = (size_t)gy*W_ + gx;
      ushort4 h = *(const ushort4*)&y1h[((size_t)b*HW_ + gpix)*64 + co4];
      f32x4 v = acc[mt][nt] + bs;
      float r0v = v.x + h2f(h.x);
      float r1v = v.y + h2f(h.y);
      float r2v = v.z + h2f(h.z);
      float r3v = v.w + h2f(h.w);
      float* yo = o + ((size_t)b*64 + co4)*HW_ + gpix;
      yo[(size_t)0*HW_] = r0v > 0.f ? r0v : 0.f;
      yo[(size_t)1*HW_] = r1v > 0.f ? r1v : 0.f;
      yo[(size_t)2*HW_] = r2v > 0.f ? r2v : 0.f;
      yo[(size_t)3*HW_] = r3v > 0.f ? r3v : 0.f;
    }
  }
}

// ---------------- attention: wave-per-point, zero block barriers, compact output ----------------
// Reads u_d/u_r PRE-scatter (conv0 outputs); writes compact (B,Ns,64) per branch.
#define FBSTR 176   // featsB row stride in bf16 (160 data + 16 pad)
#define AW 4        // waves (=points) per block

struct __align__(16) WaveShm {
  unsigned short featsB[16][FBSTR];  // 5632 B: bf16 MFMA A operand, zero-padded
  float feats[9][64];                // 2304 B: raw gathered dnn (fp32)
  float ds[64], rs[64];              // 512 B
  float attnw[2][12];                // 96 B (softmax weights, padded)
};

__global__ __launch_bounds__(256) void attn_kernel(
    const unsigned short* __restrict__ u_d, const unsigned short* __restrict__ u_r,
    const int* __restrict__ pc_idx, const int* __restrict__ nbrs_idx,
    const float* __restrict__ disp,
    const unsigned short* __restrict__ Bmlp,
    const float* __restrict__ db2v, const float* __restrict__ dw2,
    const float* __restrict__ rb2v, const float* __restrict__ rw2,
    const float* __restrict__ dbias, const float* __restrict__ rbias,
    unsigned short* __restrict__ cd, unsigned short* __restrict__ cr)
{
  __shared__ WaveShm shm[AW];
  int tid = threadIdx.x;
  int wave = tid >> 6, lane = tid & 63;
  int quad = lane >> 4, l15 = lane & 15;
  int n = blockIdx.x * AW + wave;
  int b = blockIdx.y;
  WaveShm& S = shm[wave];

  int s = pc_idx[(size_t)b*Ns_ + n];
  s = __builtin_amdgcn_readfirstlane(s);

  int myidx = (lane < 9) ? nbrs_idx[((size_t)b*Ns_ + n)*K_ + lane] : 0;
  int idx8 = __shfl(myidx, 8);

  // zero featsB (pad rows/cols must be clean for MFMA)
  {
    uint4 z = {0u,0u,0u,0u};
    unsigned short* fb = &S.featsB[0][0];
    #pragma unroll
    for (int it = 0; it < 6; ++it){
      int e = it*64 + lane;
      if (e < 16*FBSTR/8) *(uint4*)&fb[e*8] = z;
    }
  }
  // disp -> featsB[k][128+m]
  if (lane < 27){
    int m = lane / 9, k = lane - m*9;
    S.featsB[k][128 + m] = f2b(disp[(((size_t)b*3 + m)*Ns_ + n)*K_ + k]);
  }

  // gather: rows 0..7 = dnn k=0..7 (8 lanes/row, uint4 = 8 bf16)
  int grow = lane >> 3, gp = lane & 7;
  int gidx = __shfl(myidx, grow);
  uint4 g1 = *(const uint4*)&u_d[((size_t)b*HW_ + (size_t)gidx)*64 + gp*8];
  // rows 8..10: dnn k=8, ds(s from u_d), rs(s from u_r)
  uint4 g2 = {0u,0u,0u,0u};
  if (lane < 24){
    int r2 = 8 + grow;
    int idx2 = (r2 == 8) ? idx8 : s;
    const unsigned short* base = (r2 == 10) ? u_r : u_d;
    g2 = *(const uint4*)&base[((size_t)b*HW_ + (size_t)idx2)*64 + gp*8];
  }

  // feats rows 0..7 (register copy kept) ; ds/rs to LDS
  float dn[8];
  {
    const unsigned short* us = (const unsigned short*)&g1;
    #pragma unroll
    for (int j = 0; j < 8; ++j){ dn[j] = b2f(us[j]); S.feats[grow][gp*8 + j] = dn[j]; }
  }
  if (lane >= 8 && lane < 24){
    const unsigned short* us = (const unsigned short*)&g2;
    float* dst = (lane < 16) ? &S.ds[(lane - 8)*8] : &S.rs[(lane - 16)*8];
    #pragma unroll
    for (int j = 0; j < 8; ++j) dst[j] = b2f(us[j]);
  }

  // featsB rows 0..7: [dnn-ds | dnn-rs]
  {
    unsigned short od[8], orr[8];
    #pragma unroll
    for (int j = 0; j < 8; ++j){
      int c = gp*8 + j;
      od[j]  = f2b(dn[j] - S.ds[c]);
      orr[j] = f2b(dn[j] - S.rs[c]);
    }
    *(uint4*)&S.featsB[grow][gp*8]      = *(uint4*)od;
    *(uint4*)&S.featsB[grow][64 + gp*8] = *(uint4*)orr;
  }
  // row 8 (lanes 0..7 hold it in g2)
  if (lane < 8){
    const unsigned short* us = (const unsigned short*)&g2;
    unsigned short od[8], orr[8];
    #pragma unroll
    for (int j = 0; j < 8; ++j){
      int c = lane*8 + j;
      float v = b2f(us[j]);
      S.feats[8][c] = v;
      od[j]  = f2b(v - S.ds[c]);
      orr[j] = f2b(v - S.rs[c]);
    }
    *(uint4*)&S.featsB[8][lane*8]      = *(uint4*)od;
    *(uint4*)&S.featsB[8][64 + lane*8] = *(uint4*)orr;
  }

  // MLP layer-1 via MFMA: this wave does all 9 n-tiles; layer-2 partials in registers
  bf16x8 afr[5];
  #pragma unroll
  for (int ks = 0; ks < 5; ++ks)
    afr[ks] = *(const bf16x8*)&S.featsB[l15][ks*32 + quad*8];

  float pd[2][4];
  #pragma unroll
  for (int m = 0; m < 2; ++m)
    #pragma unroll
    for (int r = 0; r < 4; ++r) pd[m][r] = 0.f;

  #pragma unroll
  for (int nt = 0; nt < 9; ++nt){
    f32x4 acc = (f32x4){0.f,0.f,0.f,0.f};
    const unsigned short* bp = Bmlp + ((size_t)nt*5*64 + lane)*8;
    #pragma unroll
    for (int ks = 0; ks < 5; ++ks){
      bf16x8 bfr = *(const bf16x8*)(bp + (size_t)ks*512);
      acc = __builtin_amdgcn_mfma_f32_16x16x32_bf16(afr[ks], bfr, acc, 0, 0, 0);
    }
    int jq = nt*16 + l15;
    if (jq < 2*Dh_){
      int mlp = (jq >= Dh_) ? 1 : 0;
      int j = jq - mlp*Dh_;
      float w2 = mlp ? rw2[j] : dw2[j];
      #pragma unroll
      for (int r = 0; r < 4; ++r){
        float h = acc[r];
        h = h > 0.f ? h : 0.2f*h;     // leaky relu 0.2 (pad rows give h=0)
        pd[mlp][r] += h * w2;
      }
    }
  }

  // reduce over l15 (j dimension): xor masks 1,2,4,8
  #pragma unroll
  for (int mask = 1; mask <= 8; mask <<= 1)
    #pragma unroll
    for (int m = 0; m < 2; ++m)
      #pragma unroll
      for (int r = 0; r < 4; ++r)
        pd[m][r] += __shfl_xor(pd[m][r], mask);

  // softmax over k = quad*4 + r (valid k<9), reduced across quads via masks 16,32
  float b2c[2] = { db2v[0], rb2v[0] };
  #pragma unroll
  for (int m = 0; m < 2; ++m){
    float lg[4];
    float mx = -3.4e38f;
    #pragma unroll
    for (int r = 0; r < 4; ++r){
      lg[r] = pd[m][r] + b2c[m];
      if (quad*4 + r < 9) mx = fmaxf(mx, lg[r]);
    }
    mx = fmaxf(mx, __shfl_xor(mx, 16));
    mx = fmaxf(mx, __shfl_xor(mx, 32));
    float ex[4], sum = 0.f;
    #pragma unroll
    for (int r = 0; r < 4; ++r){
      int k = quad*4 + r;
      ex[r] = (k < 9) ? __expf(lg[r] - mx) : 0.f;
      sum += ex[r];
    }
    sum += __shfl_xor(sum, 16);
    sum += __shfl_xor(sum, 32);
    float inv = 1.f / sum;
    if (l15 == 0){
      #pragma unroll
      for (int r = 0; r < 4; ++r){
        int k = quad*4 + r;
        if (k < 9) S.attnw[m][k] = ex[r] * inv;
      }
    }
  }

  // weighted sum of raw dnn -> compact output (channel 0 replaces, others add residual)
  {
    int c = lane;
    #pragma unroll
    for (int m = 0; m < 2; ++m){
      float f = (m ? rbias : dbias)[c];
      #pragma unroll
      for (int k = 0; k < 9; ++k)
        f += S.attnw[m][k] * S.feats[k][c];
      float base = (c == 0) ? 0.f : (m ? S.rs[c] : S.ds[c]);
      unsigned short* cc_ = m ? cr : cd;
      cc_[((size_t)b*Ns_ + (size_t)n)*64 + c] = f2b(base + f);
    }
  }
}

// ---------------- scatter compact attn results into u (before conv2) ----------------
__global__ __launch_bounds__(256) void scatter_k(
    const unsigned short* __restrict__ cd, const unsigned short* __restrict__ cr,
    const int* __restrict__ pc_idx,
    unsigned short* __restrict__ u_d, unsigned short* __restrict__ u_r)
{
  int gid = blockIdx.x*256 + threadIdx.x;   // B*Ns*8 jobs, each 8 channels (uint4)
  int p = gid >> 3, q = gid & 7;
  int n = p % Ns_, b = p / Ns_;
  int s = pc_idx[(size_t)b*Ns_ + n];
  size_t so = ((size_t)b*HW_ + (size_t)s)*64 + q*8;
  size_t co = ((size_t)b*Ns_ + (size_t)n)*64 + q*8;
  *(uint4*)&u_d[so] = *(const uint4*)&cd[co];
  *(uint4*)&u_r[so] = *(const uint4*)&cr[co];
}

// ---------------- launch ----------------
extern "C" void kernel_launch(void* const* d_in, const int* in_sizes, int n_in,
                              void* d_out, int out_size, void* d_ws, size_t ws_size,
                              hipStream_t stream)
{
  (void)in_sizes; (void)n_in; (void)out_size; (void)ws_size;

  const float* rgb       = (const float*)d_in[0];
  const float* sdepth    = (const float*)d_in[1];
  const int*   pc_idx    = (const int*)d_in[2];
  const int*   nbrs_idx  = (const int*)d_in[3];
  const float* nbrs_disp = (const float*)d_in[4];

  WPtrs wp;
  wp.w[0] = (const float*)d_in[5];   // d_conv0_w
  wp.w[1] = (const float*)d_in[7];   // d_conv1_w
  wp.w[2] = (const float*)d_in[9];   // d_conv2_w
  wp.w[3] = (const float*)d_in[11];  // r_conv0_w
  wp.w[4] = (const float*)d_in[13];  // r_conv1_w
  wp.w[5] = (const float*)d_in[15];  // r_conv2_w
  const float* d_conv0_b = (const float*)d_in[6];
  const float* d_conv1_b = (const float*)d_in[8];
  const float* d_conv2_b = (const float*)d_in[10];
  const float* r_conv0_b = (const float*)d_in[12];
  const float* r_conv1_b = (const float*)d_in[14];
  const float* r_conv2_b = (const float*)d_in[16];
  const float* d_w1 = (const float*)d_in[17];
  const float* d_w2 = (const float*)d_in[19];
  const float* d_b2 = (const float*)d_in[20];
  const float* r_w1 = (const float*)d_in[21];
  const float* r_w2 = (const float*)d_in[23];
  const float* r_b2 = (const float*)d_in[24];
  const float* d_bias = (const float*)d_in[25];
  const float* r_bias = (const float*)d_in[26];

  char* ws = (char*)d_ws;
  const size_t TSZ = (size_t)B_ * HW_ * 64 * 2;   // one (B,HW,64) 2-byte tensor
  const size_t CSZ = (size_t)B_ * Ns_ * 64 * 2;   // one compact attn tensor
  unsigned short* u_d   = (unsigned short*)(ws + 0*TSZ);
  unsigned short* u_r   = (unsigned short*)(ws + 1*TSZ);
  unsigned short* y1h_d = (unsigned short*)(ws + 2*TSZ);
  unsigned short* y1h_r = (unsigned short*)(ws + 3*TSZ);
  unsigned short* cd    = (unsigned short*)(ws + 4*TSZ);
  unsigned short* cr    = (unsigned short*)(ws + 4*TSZ + CSZ);
  unsigned short* Asw   = (unsigned short*)(ws + 4*TSZ + 2*CSZ);
  unsigned short* Bmlp  = Asw + 6*CSTR;

  prep_w<<<432, 64, 0, stream>>>(wp, Asw);
  prep_wmlp<<<45, 64, 0, stream>>>(d_w1, r_w1, Bmlp);

  float* out = (float*)d_out;

  dim3 cgrid(W_/64, H_/ROWS, 4);   // z = tensor*2 + batch

  conv01_mfma<<<cgrid, 512, 0, stream>>>(sdepth, rgb, Asw,
      d_conv0_b, d_conv1_b, r_conv0_b, r_conv1_b,
      u_d, u_r, y1h_d, y1h_r);

  attn_kernel<<<dim3(Ns_/AW, B_), 256, 0, stream>>>(
      u_d, u_r, pc_idx, nbrs_idx, nbrs_disp,
      Bmlp,
      d_b2, d_w2, r_b2, r_w2,
      d_bias, r_bias,
      cd, cr);

  scatter_k<<<(B_*Ns_*8)/256, 256, 0, stream>>>(cd, cr, pc_idx, u_d, u_r);

  conv2_mfma<<<cgrid, 512, 0, stream>>>(u_d, u_r, Asw,
      d_conv2_b, r_conv2_b, y1h_d, y1h_r, out);
}